// Round 7
// baseline (610.589 us; speedup 1.0000x reference)
//
#include <hip/hip_runtime.h>

#define N_NODES 100000
#define N_EDGES 1600000
#define NODE_NF 11
#define EDGE_NF 4
#define H_NF 128
#define SCAN_B 1024
#define NBLK ((N_NODES + SCAN_B - 1) / SCAN_B)   // 98

// Edge-MLP input layout (halves): src@0..10, 0@11, dst@12..22, 0@23,
// attr@24..27, 0@28..31. K=32 MFMA window covers 0..31.
#define ASP 32    // Asort row stride (halves) = 64 B, window = 1024 B
#define K1P 40    // w1h row stride (halves)
#define K2P 136   // h / w2h row stride (halves); 272 B rows
#define EFP 131   // ef row stride (floats)
#define K1N 160   // node layer-1 padded K: nf@0..10, 0@11, agg@12..139, 0@140..159

typedef _Float16 half8 __attribute__((ext_vector_type(8)));
typedef float floatx4 __attribute__((ext_vector_type(4)));

__device__ inline half8 load8f(const float* p) {
    float4 x0 = *(const float4*)(p);
    float4 x1 = *(const float4*)(p + 4);
    half8 r;
    r[0]=(_Float16)x0.x; r[1]=(_Float16)x0.y; r[2]=(_Float16)x0.z; r[3]=(_Float16)x0.w;
    r[4]=(_Float16)x1.x; r[5]=(_Float16)x1.y; r[6]=(_Float16)x1.z; r[7]=(_Float16)x1.w;
    return r;
}
__device__ inline half8 zero8() {
    half8 z;
    #pragma unroll
    for (int j = 0; j < 8; ++j) z[j] = (_Float16)0.f;
    return z;
}

// ---------------------------------------------------------------------------
// Prep kernels
// ---------------------------------------------------------------------------
__global__ __launch_bounds__(256)
void prep_nfh(const float* __restrict__ nf, _Float16* __restrict__ nfh) {
    int i = blockIdx.x * 256 + threadIdx.x;
    if (i < N_NODES * 12) {
        int n = i / 12, k = i - n * 12;
        nfh[i] = (k < NODE_NF) ? (_Float16)nf[(size_t)n * NODE_NF + k] : (_Float16)0.f;
    }
}

// eW1 -> fp16 n-major [128][40]; e_in rows: 0..10 src, 11..21 dst, 22..25 attr.
__global__ __launch_bounds__(256)
void prep_w1h(const float* __restrict__ eW1, _Float16* __restrict__ w1h) {
    int i = blockIdx.x * 256 + threadIdx.x;
    if (i < H_NF * K1P) {
        int n = i / K1P, k = i - n * K1P;
        float v = 0.f;
        if (k < 11)                 v = eW1[k * H_NF + n];
        else if (k >= 12 && k < 23) v = eW1[(k - 1) * H_NF + n];
        else if (k >= 24 && k < 28) v = eW1[(k - 2) * H_NF + n];
        w1h[i] = (_Float16)v;
    }
}

__global__ __launch_bounds__(256)
void prep_w2h(const float* __restrict__ eW2, _Float16* __restrict__ w2h) {
    int i = blockIdx.x * 256 + threadIdx.x;
    if (i < H_NF * K2P) {
        int n = i / K2P, k = i - n * K2P;
        w2h[i] = (k < H_NF) ? (_Float16)eW2[k * H_NF + n] : (_Float16)0.f;
    }
}

__global__ __launch_bounds__(256)
void prep_w1nh(const float* __restrict__ nW1, _Float16* __restrict__ w1nh) {
    int i = blockIdx.x * 256 + threadIdx.x;
    if (i < H_NF * K1N) {
        int n = i / K1N, k = i - n * K1N;
        float v = 0.f;
        if (k < 11)                  v = nW1[k * H_NF + n];
        else if (k >= 12 && k < 140) v = nW1[(k - 1) * H_NF + n];
        w1nh[i] = (_Float16)v;
    }
}

// W23 = nW2 @ fW (no ReLU between -> exact fold), n-major [16][136]; b23.
__global__ __launch_bounds__(256)
void prep_w23(const float* __restrict__ nW2, const float* __restrict__ fW,
              const float* __restrict__ nb2, const float* __restrict__ fb,
              _Float16* __restrict__ w23h, float* __restrict__ b23) {
    int i = blockIdx.x * 256 + threadIdx.x;
    if (i < 16 * K2P) {
        int n = i / K2P, k = i - n * K2P;
        float v = 0.f;
        if (n < 4 && k < H_NF) {
            for (int j = 0; j < H_NF; ++j) v += nW2[k * H_NF + j] * fW[j * 4 + n];
        }
        w23h[i] = (_Float16)v;
    } else if (i < 16 * K2P + 4) {
        int o = i - 16 * K2P;
        float v = fb[o];
        for (int j = 0; j < H_NF; ++j) v += nb2[j] * fW[j * 4 + o];
        b23[o] = v;
    }
}

__global__ __launch_bounds__(256)
void transpose_w2(const float* __restrict__ W, float* __restrict__ WT) {
    int i = blockIdx.x * 256 + threadIdx.x;
    if (i < H_NF * H_NF) {
        int k = i >> 7, j = i & (H_NF - 1);
        WT[j * H_NF + k] = W[i];
    }
}

// ---------------------------------------------------------------------------
// Counting sort: hist -> scan -> permute.
// ---------------------------------------------------------------------------
__global__ __launch_bounds__(256)
void hist_kernel(const int* __restrict__ edge_index, int* hist) {
    int e = blockIdx.x * 256 + threadIdx.x;
    if (e < N_EDGES) atomicAdd(&hist[edge_index[e]], 1);
}

__global__ __launch_bounds__(SCAN_B)
void scan1_kernel(const int* __restrict__ hist, int* starts, int* bsum) {
    __shared__ int buf[SCAN_B];
    int i = blockIdx.x * SCAN_B + threadIdx.x;
    int v = (i < N_NODES) ? hist[i] : 0;
    buf[threadIdx.x] = v;
    __syncthreads();
    for (int off = 1; off < SCAN_B; off <<= 1) {
        int t = (threadIdx.x >= off) ? buf[threadIdx.x - off] : 0;
        __syncthreads();
        buf[threadIdx.x] += t;
        __syncthreads();
    }
    if (i < N_NODES) starts[i] = buf[threadIdx.x] - v;
    if (threadIdx.x == SCAN_B - 1) bsum[blockIdx.x] = buf[SCAN_B - 1];
}

__global__ void scan2_kernel(int* bsum) {
    if (threadIdx.x == 0 && blockIdx.x == 0) {
        int run = 0;
        for (int b = 0; b < NBLK; ++b) { int t = bsum[b]; bsum[b] = run; run += t; }
        bsum[NBLK] = run;
    }
}

__global__ __launch_bounds__(256)
void scan3_kernel(int* starts, int* cursor, const int* __restrict__ bsum) {
    int i = blockIdx.x * 256 + threadIdx.x;
    if (i < N_NODES) {
        int s = starts[i] + bsum[i / SCAN_B];
        starts[i] = s;
        cursor[i] = s;
    }
    if (i == 0) starts[N_NODES] = bsum[NBLK];
}

__global__ __launch_bounds__(256)
void permute_kernel(const int* __restrict__ edge_index, int* cursor, int* perm) {
    int e = blockIdx.x * 256 + threadIdx.x;
    if (e < N_EDGES) {
        int pos = atomicAdd(&cursor[edge_index[e]], 1);
        perm[pos] = e;
    }
}

// ---------------------------------------------------------------------------
// Gather: materialize MFMA-ready A rows in sorted order (pure TLP, hides the
// perm->edge_index->nfh dependent chain outside the hot kernel).
// Asort[i][32] halves: src@0..11(nfh row incl 0), dst@12..23, attr@24..27, 0@28..31.
// ---------------------------------------------------------------------------
__global__ __launch_bounds__(256)
void gather_kernel(const int* __restrict__ perm,
                   const int* __restrict__ edge_index,
                   const _Float16* __restrict__ nfh,
                   const float* __restrict__ edge_attr,
                   _Float16* __restrict__ Asort,
                   int* __restrict__ rows_sorted)
{
    int i = blockIdx.x * 256 + threadIdx.x;
    if (i >= N_EDGES) return;
    int e = perm[i];
    int row = edge_index[e];
    int col = edge_index[N_EDGES + e];
    rows_sorted[i] = row;
    const int2* ps = (const int2*)(nfh + (size_t)row * 12);
    const int2* pd = (const int2*)(nfh + (size_t)col * 12);
    int2 s0 = ps[0], s1 = ps[1], s2 = ps[2];
    int2 d0 = pd[0], d1 = pd[1], d2 = pd[2];
    float4 a4 = ((const float4*)edge_attr)[e];
    union { _Float16 h[4]; int2 v; } u;
    u.h[0] = (_Float16)a4.x; u.h[1] = (_Float16)a4.y;
    u.h[2] = (_Float16)a4.z; u.h[3] = (_Float16)a4.w;
    int2* op = (int2*)(Asort + (size_t)i * ASP);
    op[0] = s0; op[1] = s1; op[2] = s2;
    op[3] = d0; op[4] = d1; op[5] = d2;
    op[6] = u.v; op[7] = make_int2(0, 0);
}

// ---------------------------------------------------------------------------
// Edge MLP v3: persistent, barrier-free, weights in REGISTERS.
// Per 16-edge window: A-frag direct from global (prefetched 1 window ahead)
// -> 8 MFMA (L1) -> h via per-wave LDS -> 32 MFMA (L2, reg B-frags) -> ef LDS
// -> serial segmented reduction -> sparse atomics. No block barrier at all.
// ---------------------------------------------------------------------------
#define E_ARENA_SZ 8448   // Hs@0 (4352) / ef@0 (8384, overlays Hs) / rows@8384 (64)

__global__ __launch_bounds__(256, 2)
void edge_mfma_kernel(const _Float16* __restrict__ Asort,
                      const int*   __restrict__ rows_sorted,
                      const _Float16* __restrict__ w1h,
                      const float* __restrict__ eb1,
                      const _Float16* __restrict__ w2h,
                      const float* __restrict__ eb2,
                      float* agg)   // [N_NODES][H_NF]
{
    __shared__ __align__(16) char smem[4 * E_ARENA_SZ];
    int t = threadIdx.x;
    int wv = t >> 6, lane = t & 63;
    char* arena = smem + wv * E_ARENA_SZ;
    _Float16* Hs   = (_Float16*)arena;
    float*    efS  = (float*)arena;          // overlays Hs (same-wave in-order LDS)
    int*      rowsS = (int*)(arena + 8384);
    int m = lane & 15, quad = lane >> 4;

    // loop-invariant weight fragments -> VGPRs
    half8 w1f[8], w2f[8][4];
    #pragma unroll
    for (int tile = 0; tile < 8; ++tile)
        w1f[tile] = *(const half8*)(w1h + (tile * 16 + m) * K1P + quad * 8);
    #pragma unroll
    for (int tile = 0; tile < 8; ++tile)
        #pragma unroll
        for (int ks = 0; ks < 4; ++ks)
            w2f[tile][ks] = *(const half8*)(w2h + (tile * 16 + m) * K2P + ks * 32 + quad * 8);
    float b1v[8], b2v[8];
    #pragma unroll
    for (int tile = 0; tile < 8; ++tile) {
        b1v[tile] = eb1[tile * 16 + m];
        b2v[tile] = eb2[tile * 16 + m];
    }

    const int nwin = N_EDGES / 16;           // 100000
    const int STRIDE = gridDim.x * 4;
    int win = blockIdx.x * 4 + wv;
    if (win >= nwin) return;

    half8 a1 = *(const half8*)(Asort + (size_t)win * (16 * ASP) + m * ASP + quad * 8);
    int rs = (quad == 3) ? rows_sorted[win * 16 + m] : 0;

    while (true) {
        int next = win + STRIDE;
        bool hn = next < nwin;
        if (quad == 3) rowsS[m] = rs;        // publish current rows (same-wave order)
        half8 a1n = {};
        int rsn = 0;
        if (hn) {                            // prefetch next window
            a1n = *(const half8*)(Asort + (size_t)next * (16 * ASP) + m * ASP + quad * 8);
            if (quad == 3) rsn = rows_sorted[next * 16 + m];
        }

        // ---- layer 1: 26(pad32) -> 128 ----
        #pragma unroll
        for (int tile = 0; tile < 8; ++tile) {
            floatx4 c = {0.f, 0.f, 0.f, 0.f};
            c = __builtin_amdgcn_mfma_f32_16x16x32_f16(a1, w1f[tile], c, 0, 0, 0);
            int n = tile * 16 + m;
            #pragma unroll
            for (int r = 0; r < 4; ++r)
                Hs[(quad * 4 + r) * K2P + n] = (_Float16)fmaxf(c[r] + b1v[tile], 0.f);
        }

        // ---- layer 2 A-frags ----
        half8 a2[4];
        #pragma unroll
        for (int ks = 0; ks < 4; ++ks)
            a2[ks] = *(const half8*)(Hs + m * K2P + ks * 32 + quad * 8);

        // ---- layer 2: 128 -> 128, write ef directly ----
        #pragma unroll
        for (int tile = 0; tile < 8; ++tile) {
            floatx4 c = {0.f, 0.f, 0.f, 0.f};
            #pragma unroll
            for (int ks = 0; ks < 4; ++ks)
                c = __builtin_amdgcn_mfma_f32_16x16x32_f16(a2[ks], w2f[tile][ks], c, 0, 0, 0);
            #pragma unroll
            for (int r = 0; r < 4; ++r)
                efS[(quad * 4 + r) * EFP + tile * 16 + m] = fmaxf(c[r] + b2v[tile], 0.f);
        }

        // ---- segmented reduction over 16 sorted edges; 2 features/lane ----
        int f = lane;
        int cur = rowsS[0];
        float acc0 = efS[f], acc1 = efS[64 + f];
        #pragma unroll 1
        for (int i = 1; i < 16; ++i) {
            int r = rowsS[i];                       // wave-uniform
            float v0 = efS[i * EFP + f];
            float v1 = efS[i * EFP + 64 + f];
            if (r != cur) {                         // wave-uniform branch
                unsafeAtomicAdd(&agg[(size_t)cur * H_NF + f], acc0);
                unsafeAtomicAdd(&agg[(size_t)cur * H_NF + 64 + f], acc1);
                acc0 = v0; acc1 = v1; cur = r;
            } else { acc0 += v0; acc1 += v1; }
        }
        unsafeAtomicAdd(&agg[(size_t)cur * H_NF + f], acc0);
        unsafeAtomicAdd(&agg[(size_t)cur * H_NF + 64 + f], acc1);

        if (!hn) break;
        win = next; a1 = a1n; rs = rsn;
    }
}

// ---------------------------------------------------------------------------
// Tier-2 edge kernel (R6): in-kernel gather via perm. Used if ws can't fit Asort.
// ---------------------------------------------------------------------------
#define G_W1      0
#define G_W2      10240
#define G_ARENA   45056
#define G_ARENA_SZ 8448
#define G_TOTAL   (G_ARENA + 4 * G_ARENA_SZ)
#define K1PG 40

__global__ __launch_bounds__(256, 2)
void edge_mfma_gather_kernel(const _Float16* __restrict__ nfh,
                             const int*   __restrict__ edge_index,
                             const float* __restrict__ edge_attr,
                             const _Float16* __restrict__ w1h,
                             const float* __restrict__ eb1,
                             const _Float16* __restrict__ w2h,
                             const float* __restrict__ eb2,
                             const int*   __restrict__ perm,
                             float* agg)
{
    __shared__ __align__(16) char smem[G_TOTAL];
    _Float16* W1s = (_Float16*)(smem + G_W1);
    _Float16* W2s = (_Float16*)(smem + G_W2);
    int t = threadIdx.x;
    {
        const float4* g1 = (const float4*)w1h;
        float4* s1 = (float4*)W1s;
        for (int i = t; i < 640; i += 256) s1[i] = g1[i];
        const float4* g2 = (const float4*)w2h;
        float4* s2 = (float4*)W2s;
        for (int i = t; i < 2176; i += 256) s2[i] = g2[i];
    }
    __syncthreads();

    int wv = t >> 6, lane = t & 63;
    char* arena = smem + G_ARENA + wv * G_ARENA_SZ;
    _Float16* Ain  = (_Float16*)arena;
    _Float16* Hs   = (_Float16*)(arena + 1280);
    float*    efS  = (float*)arena;
    int*      rowsS = (int*)(arena + 8384);

    int m = lane & 15, quad = lane >> 4;
    int el = lane & 15, grp = lane >> 4;
    _Float16* arow = Ain + el * K1PG;

    float b1v[8], b2v[8];
    #pragma unroll
    for (int tile = 0; tile < 8; ++tile) {
        b1v[tile] = eb1[tile * 16 + m];
        b2v[tile] = eb2[tile * 16 + m];
    }

    const int nwin = N_EDGES / 16;
    for (int win = blockIdx.x * 4 + wv; win < nwin; win += gridDim.x * 4) {
        int e = perm[win * 16 + el];
        if (grp < 2) {
            int node = edge_index[grp * N_EDGES + e];
            const int2* p = (const int2*)(nfh + (size_t)node * 12);
            int2 x0 = p[0], x1 = p[1], x2 = p[2];
            char* dst = (char*)(arow + grp * 12);
            *(int2*)(dst) = x0; *(int2*)(dst + 8) = x1; *(int2*)(dst + 16) = x2;
        } else if (grp == 2) {
            float4 a4 = ((const float4*)edge_attr)[e];
            arow[24] = (_Float16)a4.x; arow[25] = (_Float16)a4.y;
            arow[26] = (_Float16)a4.z; arow[27] = (_Float16)a4.w;
        } else {
            rowsS[el] = edge_index[e];
            *(int2*)((char*)arow + 56) = make_int2(0, 0);
        }

        half8 a1 = *(const half8*)(Ain + m * K1PG + quad * 8);
        #pragma unroll
        for (int tile = 0; tile < 8; ++tile) {
            half8 b = *(const half8*)(W1s + (tile * 16 + m) * K1PG + quad * 8);
            floatx4 c = {0.f, 0.f, 0.f, 0.f};
            c = __builtin_amdgcn_mfma_f32_16x16x32_f16(a1, b, c, 0, 0, 0);
            int n = tile * 16 + m;
            #pragma unroll
            for (int r = 0; r < 4; ++r)
                Hs[(quad * 4 + r) * K2P + n] = (_Float16)fmaxf(c[r] + b1v[tile], 0.f);
        }
        half8 a2[4];
        #pragma unroll
        for (int ks = 0; ks < 4; ++ks)
            a2[ks] = *(const half8*)(Hs + m * K2P + ks * 32 + quad * 8);
        float vals[32];
        #pragma unroll
        for (int tile = 0; tile < 8; ++tile) {
            floatx4 c = {0.f, 0.f, 0.f, 0.f};
            #pragma unroll
            for (int ks = 0; ks < 4; ++ks) {
                half8 b = *(const half8*)(W2s + (tile * 16 + m) * K2P + ks * 32 + quad * 8);
                c = __builtin_amdgcn_mfma_f32_16x16x32_f16(a2[ks], b, c, 0, 0, 0);
            }
            #pragma unroll
            for (int r = 0; r < 4; ++r)
                vals[tile * 4 + r] = fmaxf(c[r] + b2v[tile], 0.f);
        }
        #pragma unroll
        for (int tile = 0; tile < 8; ++tile)
            #pragma unroll
            for (int r = 0; r < 4; ++r)
                efS[(quad * 4 + r) * EFP + tile * 16 + m] = vals[tile * 4 + r];

        int f = lane;
        int cur = rowsS[0];
        float acc0 = efS[f], acc1 = efS[64 + f];
        #pragma unroll 1
        for (int i = 1; i < 16; ++i) {
            int r = rowsS[i];
            float v0 = efS[i * EFP + f];
            float v1 = efS[i * EFP + 64 + f];
            if (r != cur) {
                unsafeAtomicAdd(&agg[(size_t)cur * H_NF + f], acc0);
                unsafeAtomicAdd(&agg[(size_t)cur * H_NF + 64 + f], acc1);
                acc0 = v0; acc1 = v1; cur = r;
            } else { acc0 += v0; acc1 += v1; }
        }
        unsafeAtomicAdd(&agg[(size_t)cur * H_NF + f], acc0);
        unsafeAtomicAdd(&agg[(size_t)cur * H_NF + 64 + f], acc1);
    }
}

// ---------------------------------------------------------------------------
// Fused node pipeline, persistent: weights staged ONCE per block, then loop
// over 64-node tiles. n_h via per-wave LDS; fc_emb folded into layer 2.
// ---------------------------------------------------------------------------
#define N_W1    0                         // 128*160*2 = 40960
#define N_W23   40960                     // 16*136*2  = 4352 -> 45312
#define N_HS    45312                     // + 4*4352 -> 62720

__global__ __launch_bounds__(256, 2)
void node_mfma_kernel(const float* __restrict__ node_feats,
                      const float* __restrict__ agg,
                      const _Float16* __restrict__ w1nh,
                      const float* __restrict__ nb1,
                      const _Float16* __restrict__ w23h,
                      const float* __restrict__ b23,
                      float* __restrict__ out)
{
    __shared__ __align__(16) char smem[N_HS + 4 * 4352];
    _Float16* W1N  = (_Float16*)(smem + N_W1);
    _Float16* W23s = (_Float16*)(smem + N_W23);
    int t = threadIdx.x;
    {
        const float4* g1 = (const float4*)w1nh;
        float4* s1 = (float4*)W1N;
        for (int i = t; i < 2560; i += 256) s1[i] = g1[i];
        const float4* g2 = (const float4*)w23h;
        float4* s2 = (float4*)W23s;
        for (int i = t; i < 272; i += 256) s2[i] = g2[i];
    }
    __syncthreads();

    int wv = t >> 6, lane = t & 63;
    int m = lane & 15, quad = lane >> 4;
    _Float16* HsW = (_Float16*)(smem + N_HS + wv * 4352);
    const int ntile = (N_NODES + 63) / 64;   // 1563

    for (int ti = blockIdx.x; ti < ntile; ti += gridDim.x) {
        int nb = (ti * 4 + wv) * 16;
        if (nb >= N_NODES) continue;
        int nodeA = nb + m;
        if (nodeA >= N_NODES) nodeA = N_NODES - 1;
        const float* ag  = agg + (size_t)nodeA * H_NF;
        const float* nfp = node_feats + (size_t)nodeA * NODE_NF;

        half8 afr[5];
        if (quad == 0) {
            half8 r;
            #pragma unroll
            for (int j = 0; j < 8; ++j) r[j] = (_Float16)nfp[j];
            afr[0] = r;
            afr[4] = load8f(ag + 116);
        } else if (quad == 1) {
            half8 r;
            r[0] = (_Float16)nfp[8]; r[1] = (_Float16)nfp[9];
            r[2] = (_Float16)nfp[10]; r[3] = (_Float16)0.f;
            float4 x = *(const float4*)(ag);
            r[4] = (_Float16)x.x; r[5] = (_Float16)x.y;
            r[6] = (_Float16)x.z; r[7] = (_Float16)x.w;
            afr[0] = r;
            float4 y = *(const float4*)(ag + 124);
            half8 s = zero8();
            s[0] = (_Float16)y.x; s[1] = (_Float16)y.y;
            s[2] = (_Float16)y.z; s[3] = (_Float16)y.w;
            afr[4] = s;
        } else if (quad == 2) {
            afr[0] = load8f(ag + 4);
            afr[4] = zero8();
        } else {
            afr[0] = load8f(ag + 12);
            afr[4] = zero8();
        }
        afr[1] = load8f(ag + 20 + 8 * quad);
        afr[2] = load8f(ag + 52 + 8 * quad);
        afr[3] = load8f(ag + 84 + 8 * quad);

        #pragma unroll
        for (int tile = 0; tile < 8; ++tile) {
            floatx4 c = {0.f, 0.f, 0.f, 0.f};
            #pragma unroll
            for (int ks = 0; ks < 5; ++ks) {
                half8 b = *(const half8*)(W1N + (tile * 16 + m) * K1N + ks * 32 + quad * 8);
                c = __builtin_amdgcn_mfma_f32_16x16x32_f16(afr[ks], b, c, 0, 0, 0);
            }
            float bv = nb1[tile * 16 + m];
            #pragma unroll
            for (int r = 0; r < 4; ++r)
                HsW[(quad * 4 + r) * K2P + tile * 16 + m] = (_Float16)fmaxf(c[r] + bv, 0.f);
        }

        half8 a2[4];
        #pragma unroll
        for (int ks = 0; ks < 4; ++ks)
            a2[ks] = *(const half8*)(HsW + m * K2P + ks * 32 + quad * 8);
        floatx4 c23 = {0.f, 0.f, 0.f, 0.f};
        #pragma unroll
        for (int ks = 0; ks < 4; ++ks) {
            half8 b = *(const half8*)(W23s + m * K2P + ks * 32 + quad * 8);
            c23 = __builtin_amdgcn_mfma_f32_16x16x32_f16(a2[ks], b, c23, 0, 0, 0);
        }
        if (m < 4) {
            float bv = b23[m];
            #pragma unroll
            for (int r = 0; r < 4; ++r) {
                int node = nb + quad * 4 + r;
                if (node < N_NODES) out[node * 4 + m] = c23[r] + bv;
            }
        }
    }
}

// ---------------------------------------------------------------------------
// Tier-3 fp32 fallback.
// ---------------------------------------------------------------------------
__global__ __launch_bounds__(256)
void edge_kernel_atomic(const float* __restrict__ node_feats,
                        const int*   __restrict__ edge_index,
                        const float* __restrict__ edge_attr,
                        const float* __restrict__ eW1,
                        const float* __restrict__ eb1,
                        const float* __restrict__ W2T,
                        const float* __restrict__ eb2,
                        float* agg)
{
    int e = blockIdx.x * 256 + threadIdx.x;
    if (e >= N_EDGES) return;
    int row = edge_index[e];
    int col = edge_index[N_EDGES + e];
    float h[H_NF];
    #pragma unroll
    for (int j = 0; j < H_NF; ++j) h[j] = eb1[j];
    const float* srcp = node_feats + (size_t)row * NODE_NF;
    #pragma unroll 1
    for (int k = 0; k < NODE_NF; ++k) {
        float x = srcp[k];
        const float* w = eW1 + k * H_NF;
        #pragma unroll
        for (int j = 0; j < H_NF; ++j) h[j] = fmaf(x, w[j], h[j]);
    }
    const float* dstp = node_feats + (size_t)col * NODE_NF;
    #pragma unroll 1
    for (int k = 0; k < NODE_NF; ++k) {
        float x = dstp[k];
        const float* w = eW1 + (NODE_NF + k) * H_NF;
        #pragma unroll
        for (int j = 0; j < H_NF; ++j) h[j] = fmaf(x, w[j], h[j]);
    }
    float4 at = ((const float4*)edge_attr)[e];
    float av[EDGE_NF] = {at.x, at.y, at.z, at.w};
    #pragma unroll
    for (int k = 0; k < EDGE_NF; ++k) {
        float x = av[k];
        const float* w = eW1 + (2 * NODE_NF + k) * H_NF;
        #pragma unroll
        for (int j = 0; j < H_NF; ++j) h[j] = fmaf(x, w[j], h[j]);
    }
    #pragma unroll
    for (int j = 0; j < H_NF; ++j) h[j] = fmaxf(h[j], 0.f);
    #pragma unroll 1
    for (int j0 = 0; j0 < H_NF; j0 += 8) {
        float acc[8];
        #pragma unroll
        for (int jj = 0; jj < 8; ++jj) acc[jj] = eb2[j0 + jj];
        #pragma unroll
        for (int k = 0; k < H_NF; ++k) {
            float x = h[k];
            #pragma unroll
            for (int jj = 0; jj < 8; ++jj)
                acc[jj] = fmaf(x, W2T[(j0 + jj) * H_NF + k], acc[jj]);
        }
        #pragma unroll
        for (int jj = 0; jj < 8; ++jj)
            unsafeAtomicAdd(&agg[(size_t)row * H_NF + j0 + jj], fmaxf(acc[jj], 0.f));
    }
}

__global__ __launch_bounds__(256)
void node_kernel1(const float* __restrict__ node_feats, float* agg_nh,
                  const float* __restrict__ nW1, const float* __restrict__ nb1)
{
    int n = blockIdx.x * 256 + threadIdx.x;
    if (n >= N_NODES) return;
    float acc[H_NF];
    #pragma unroll
    for (int j = 0; j < H_NF; ++j) acc[j] = nb1[j];
    const float* nfp = node_feats + (size_t)n * NODE_NF;
    #pragma unroll 1
    for (int k = 0; k < NODE_NF; ++k) {
        float x = nfp[k];
        const float* w = nW1 + k * H_NF;
        #pragma unroll
        for (int j = 0; j < H_NF; ++j) acc[j] = fmaf(x, w[j], acc[j]);
    }
    const float4* ap = (const float4*)(agg_nh + (size_t)n * H_NF);
    #pragma unroll 1
    for (int k4 = 0; k4 < H_NF / 4; ++k4) {
        float4 x = ap[k4];
        const float* w0 = nW1 + (NODE_NF + k4 * 4 + 0) * H_NF;
        const float* w1 = nW1 + (NODE_NF + k4 * 4 + 1) * H_NF;
        const float* w2 = nW1 + (NODE_NF + k4 * 4 + 2) * H_NF;
        const float* w3 = nW1 + (NODE_NF + k4 * 4 + 3) * H_NF;
        #pragma unroll
        for (int j = 0; j < H_NF; ++j) {
            acc[j] = fmaf(x.x, w0[j], acc[j]);
            acc[j] = fmaf(x.y, w1[j], acc[j]);
            acc[j] = fmaf(x.z, w2[j], acc[j]);
            acc[j] = fmaf(x.w, w3[j], acc[j]);
        }
    }
    float* op = agg_nh + (size_t)n * H_NF;
    #pragma unroll
    for (int j4 = 0; j4 < H_NF / 4; ++j4) {
        float4 o = make_float4(fmaxf(acc[j4*4+0], 0.f), fmaxf(acc[j4*4+1], 0.f),
                               fmaxf(acc[j4*4+2], 0.f), fmaxf(acc[j4*4+3], 0.f));
        ((float4*)op)[j4] = o;
    }
}

__global__ __launch_bounds__(256)
void node_kernel2(const float* __restrict__ nh, const float* __restrict__ nW2,
                  const float* __restrict__ nb2, const float* __restrict__ fW,
                  const float* __restrict__ fb, float* __restrict__ out)
{
    int n = blockIdx.x * 256 + threadIdx.x;
    if (n >= N_NODES) return;
    float acc[H_NF];
    #pragma unroll
    for (int j = 0; j < H_NF; ++j) acc[j] = nb2[j];
    const float4* hp = (const float4*)(nh + (size_t)n * H_NF);
    #pragma unroll 1
    for (int k4 = 0; k4 < H_NF / 4; ++k4) {
        float4 x = hp[k4];
        const float* w0 = nW2 + (k4 * 4 + 0) * H_NF;
        const float* w1 = nW2 + (k4 * 4 + 1) * H_NF;
        const float* w2 = nW2 + (k4 * 4 + 2) * H_NF;
        const float* w3 = nW2 + (k4 * 4 + 3) * H_NF;
        #pragma unroll
        for (int j = 0; j < H_NF; ++j) {
            acc[j] = fmaf(x.x, w0[j], acc[j]);
            acc[j] = fmaf(x.y, w1[j], acc[j]);
            acc[j] = fmaf(x.z, w2[j], acc[j]);
            acc[j] = fmaf(x.w, w3[j], acc[j]);
        }
    }
    float o0 = fb[0], o1 = fb[1], o2 = fb[2], o3 = fb[3];
    #pragma unroll
    for (int j = 0; j < H_NF; ++j) {
        o0 = fmaf(acc[j], fW[j * 4 + 0], o0);
        o1 = fmaf(acc[j], fW[j * 4 + 1], o1);
        o2 = fmaf(acc[j], fW[j * 4 + 2], o2);
        o3 = fmaf(acc[j], fW[j * 4 + 3], o3);
    }
    ((float4*)out)[n] = make_float4(o0, o1, o2, o3);
}

extern "C" void kernel_launch(void* const* d_in, const int* in_sizes, int n_in,
                              void* d_out, int out_size, void* d_ws, size_t ws_size,
                              hipStream_t stream)
{
    const float* node_feats = (const float*)d_in[0];
    const int*   edge_index = (const int*)d_in[1];
    const float* edge_attr  = (const float*)d_in[2];
    const float* eW1 = (const float*)d_in[3];
    const float* eb1 = (const float*)d_in[4];
    const float* eW2 = (const float*)d_in[5];
    const float* eb2 = (const float*)d_in[6];
    const float* nW1 = (const float*)d_in[7];
    const float* nb1 = (const float*)d_in[8];
    const float* nW2 = (const float*)d_in[9];
    const float* nb2 = (const float*)d_in[10];
    const float* fW  = (const float*)d_in[11];
    const float* fb  = (const float*)d_in[12];
    float* out = (float*)d_out;

    // ---- workspace carve-up (256B aligned) ----
    size_t off = 0;
    auto carve = [&](size_t bytes) {
        void* p = (char*)d_ws + off;
        off = (off + bytes + 255) & ~(size_t)255;
        return p;
    };
    float*     agg    = (float*)carve((size_t)N_NODES * H_NF * sizeof(float)); // 51.2 MB
    int*       perm   = (int*)  carve((size_t)N_EDGES * sizeof(int));          // 6.4 MB
    int*       hist   = (int*)  carve((size_t)N_NODES * sizeof(int));
    int*       starts = (int*)  carve((size_t)(N_NODES + 1) * sizeof(int));
    int*       cursor = (int*)  carve((size_t)N_NODES * sizeof(int));
    int*       bsum   = (int*)  carve((size_t)(NBLK + 1) * sizeof(int));
    _Float16*  nfh    = (_Float16*)carve((size_t)N_NODES * 12 * sizeof(_Float16)); // 2.4 MB
    _Float16*  w1h    = (_Float16*)carve((size_t)H_NF * K1P * sizeof(_Float16));
    _Float16*  w2h    = (_Float16*)carve((size_t)H_NF * K2P * sizeof(_Float16));
    _Float16*  w1nh   = (_Float16*)carve((size_t)H_NF * K1N * sizeof(_Float16));
    _Float16*  w23h   = (_Float16*)carve((size_t)16 * K2P * sizeof(_Float16));
    float*     b23    = (float*)carve(4 * sizeof(float));
    size_t required_t2 = off;
    _Float16*  Asort  = (_Float16*)carve((size_t)N_EDGES * ASP * sizeof(_Float16)); // 102.4 MB
    int*       rowsS  = (int*)carve((size_t)N_EDGES * sizeof(int));                 // 6.4 MB
    size_t required_t1 = off;

    if (ws_size >= required_t2) {
        // shared prep + sort
        prep_nfh <<<(N_NODES * 12 + 255) / 256, 256, 0, stream>>>(node_feats, nfh);
        prep_w1h <<<(H_NF * K1P + 255) / 256, 256, 0, stream>>>(eW1, w1h);
        prep_w2h <<<(H_NF * K2P + 255) / 256, 256, 0, stream>>>(eW2, w2h);
        prep_w1nh<<<(H_NF * K1N + 255) / 256, 256, 0, stream>>>(nW1, w1nh);
        prep_w23 <<<(16 * K2P + 4 + 255) / 256, 256, 0, stream>>>(nW2, fW, nb2, fb, w23h, b23);
        hipMemsetAsync(agg, 0, (size_t)N_NODES * H_NF * sizeof(float), stream);
        hipMemsetAsync(hist, 0, (size_t)N_NODES * sizeof(int), stream);
        hist_kernel<<<(N_EDGES + 255) / 256, 256, 0, stream>>>(edge_index, hist);
        scan1_kernel<<<NBLK, SCAN_B, 0, stream>>>(hist, starts, bsum);
        scan2_kernel<<<1, 64, 0, stream>>>(bsum);
        scan3_kernel<<<(N_NODES + 255) / 256, 256, 0, stream>>>(starts, cursor, bsum);
        permute_kernel<<<(N_EDGES + 255) / 256, 256, 0, stream>>>(edge_index, cursor, perm);

        if (ws_size >= required_t1) {
            gather_kernel<<<(N_EDGES + 255) / 256, 256, 0, stream>>>(
                perm, edge_index, nfh, edge_attr, Asort, rowsS);
            edge_mfma_kernel<<<512, 256, 0, stream>>>(
                Asort, rowsS, w1h, eb1, w2h, eb2, agg);
        } else {
            edge_mfma_gather_kernel<<<512, 256, 0, stream>>>(
                nfh, edge_index, edge_attr, w1h, eb1, w2h, eb2, perm, agg);
        }
        node_mfma_kernel<<<512, 256, 0, stream>>>(
            node_feats, agg, w1nh, nb1, w23h, b23, out);
    } else {
        // tier 3: fp32 atomic scatter path
        float* agg_fb = (float*)d_ws;
        float* W2T_fb = (float*)((char*)d_ws + (size_t)N_NODES * H_NF * sizeof(float));
        transpose_w2<<<(H_NF * H_NF + 255) / 256, 256, 0, stream>>>(eW2, W2T_fb);
        hipMemsetAsync(agg_fb, 0, (size_t)N_NODES * H_NF * sizeof(float), stream);
        edge_kernel_atomic<<<(N_EDGES + 255) / 256, 256, 0, stream>>>(
            node_feats, edge_index, edge_attr, eW1, eb1, W2T_fb, eb2, agg_fb);
        node_kernel1<<<(N_NODES + 255) / 256, 256, 0, stream>>>(node_feats, agg_fb, nW1, nb1);
        node_kernel2<<<(N_NODES + 255) / 256, 256, 0, stream>>>(agg_fb, nW2, nb2, fW, fb, out);
    }
}

// Round 8
// 548.941 us; speedup vs baseline: 1.1123x; 1.1123x over previous
//
#include <hip/hip_runtime.h>

#define N_NODES 100000
#define N_EDGES 1600000
#define NODE_NF 11
#define EDGE_NF 4
#define H_NF 128
#define SCAN_B 1024
#define NBLK ((N_NODES + SCAN_B - 1) / SCAN_B)   // 98

// Edge-MLP input layout (halves): src@0..10, 0@11, dst@12..22, 0@23,
// attr@24..27, 0@28..31. K=32 MFMA window covers 0..31.
#define ASP 32    // Asort row stride (halves) = 64 B
#define K1P 40    // w1h row stride (halves)
#define K2P 136   // h / w2h row stride (halves)
#define EFP 131   // ef row stride (floats)
#define K1N 160   // node layer-1 padded K

typedef _Float16 half8 __attribute__((ext_vector_type(8)));
typedef float floatx4 __attribute__((ext_vector_type(4)));

__device__ inline half8 load8f(const float* p) {
    float4 x0 = *(const float4*)(p);
    float4 x1 = *(const float4*)(p + 4);
    half8 r;
    r[0]=(_Float16)x0.x; r[1]=(_Float16)x0.y; r[2]=(_Float16)x0.z; r[3]=(_Float16)x0.w;
    r[4]=(_Float16)x1.x; r[5]=(_Float16)x1.y; r[6]=(_Float16)x1.z; r[7]=(_Float16)x1.w;
    return r;
}
__device__ inline half8 zero8() {
    half8 z;
    #pragma unroll
    for (int j = 0; j < 8; ++j) z[j] = (_Float16)0.f;
    return z;
}

// ---------------------------------------------------------------------------
// Fused prep + hist: one launch does all weight/feature conversions AND the
// degree histogram, via flat-index segments.
// ---------------------------------------------------------------------------
#define SEG0 (N_NODES * 12)            // nfh
#define SEG1 (SEG0 + H_NF * K1P)       // w1h
#define SEG2 (SEG1 + H_NF * K2P)       // w2h
#define SEG3 (SEG2 + H_NF * K1N)       // w1nh
#define SEG4 (SEG3 + 16 * K2P + 4)     // w23h + b23
#define SEG5 (SEG4 + N_EDGES)          // hist

__global__ __launch_bounds__(256)
void prep_hist_kernel(const float* __restrict__ nf,
                      const float* __restrict__ eW1,
                      const float* __restrict__ eW2,
                      const float* __restrict__ nW1,
                      const float* __restrict__ nW2,
                      const float* __restrict__ fW,
                      const float* __restrict__ nb2,
                      const float* __restrict__ fb,
                      const int*   __restrict__ edge_index,
                      _Float16* __restrict__ nfh,
                      _Float16* __restrict__ w1h,
                      _Float16* __restrict__ w2h,
                      _Float16* __restrict__ w1nh,
                      _Float16* __restrict__ w23h,
                      float* __restrict__ b23,
                      int* hist)
{
    int i = blockIdx.x * 256 + threadIdx.x;
    if (i < SEG0) {
        int n = i / 12, k = i - n * 12;
        nfh[i] = (k < NODE_NF) ? (_Float16)nf[(size_t)n * NODE_NF + k] : (_Float16)0.f;
    } else if (i < SEG1) {
        int j = i - SEG0;
        int n = j / K1P, k = j - n * K1P;
        float v = 0.f;
        if (k < 11)                 v = eW1[k * H_NF + n];
        else if (k >= 12 && k < 23) v = eW1[(k - 1) * H_NF + n];
        else if (k >= 24 && k < 28) v = eW1[(k - 2) * H_NF + n];
        w1h[j] = (_Float16)v;
    } else if (i < SEG2) {
        int j = i - SEG1;
        int n = j / K2P, k = j - n * K2P;
        w2h[j] = (k < H_NF) ? (_Float16)eW2[k * H_NF + n] : (_Float16)0.f;
    } else if (i < SEG3) {
        int j = i - SEG2;
        int n = j / K1N, k = j - n * K1N;
        float v = 0.f;
        if (k < 11)                  v = nW1[k * H_NF + n];
        else if (k >= 12 && k < 140) v = nW1[(k - 1) * H_NF + n];
        w1nh[j] = (_Float16)v;
    } else if (i < SEG4) {
        int j = i - SEG3;
        if (j < 16 * K2P) {
            int n = j / K2P, k = j - n * K2P;
            float v = 0.f;
            if (n < 4 && k < H_NF) {
                for (int q = 0; q < H_NF; ++q) v += nW2[k * H_NF + q] * fW[q * 4 + n];
            }
            w23h[j] = (_Float16)v;
        } else {
            int o = j - 16 * K2P;
            float v = fb[o];
            for (int q = 0; q < H_NF; ++q) v += nb2[q] * fW[q * 4 + o];
            b23[o] = v;
        }
    } else if (i < SEG5) {
        int e = i - SEG4;
        atomicAdd(&hist[edge_index[e]], 1);
    }
}

__global__ __launch_bounds__(256)
void transpose_w2(const float* __restrict__ W, float* __restrict__ WT) {
    int i = blockIdx.x * 256 + threadIdx.x;
    if (i < H_NF * H_NF) {
        int k = i >> 7, j = i & (H_NF - 1);
        WT[j * H_NF + k] = W[i];
    }
}

// ---------------------------------------------------------------------------
// Scan chain.
// ---------------------------------------------------------------------------
__global__ __launch_bounds__(SCAN_B)
void scan1_kernel(const int* __restrict__ hist, int* starts, int* bsum) {
    __shared__ int buf[SCAN_B];
    int i = blockIdx.x * SCAN_B + threadIdx.x;
    int v = (i < N_NODES) ? hist[i] : 0;
    buf[threadIdx.x] = v;
    __syncthreads();
    for (int off = 1; off < SCAN_B; off <<= 1) {
        int t = (threadIdx.x >= off) ? buf[threadIdx.x - off] : 0;
        __syncthreads();
        buf[threadIdx.x] += t;
        __syncthreads();
    }
    if (i < N_NODES) starts[i] = buf[threadIdx.x] - v;
    if (threadIdx.x == SCAN_B - 1) bsum[blockIdx.x] = buf[SCAN_B - 1];
}

__global__ void scan2_kernel(int* bsum) {
    if (threadIdx.x == 0 && blockIdx.x == 0) {
        int run = 0;
        for (int b = 0; b < NBLK; ++b) { int t = bsum[b]; bsum[b] = run; run += t; }
        bsum[NBLK] = run;
    }
}

__global__ __launch_bounds__(256)
void scan3_kernel(int* starts, int* cursor, const int* __restrict__ bsum) {
    int i = blockIdx.x * 256 + threadIdx.x;
    if (i < N_NODES) {
        int s = starts[i] + bsum[i / SCAN_B];
        starts[i] = s;
        cursor[i] = s;
    }
    if (i == 0) starts[N_NODES] = bsum[NBLK];
}

// ---------------------------------------------------------------------------
// Fused permute + gather: compute sorted position AND materialize the
// MFMA-ready A row directly at Asort[pos] (scattered 64B stores). No perm
// buffer, no second pass.
// ---------------------------------------------------------------------------
__global__ __launch_bounds__(256)
void permgather_kernel(const int* __restrict__ edge_index,
                       const _Float16* __restrict__ nfh,
                       const float* __restrict__ edge_attr,
                       int* cursor,
                       _Float16* __restrict__ Asort,
                       int* __restrict__ rows_sorted)
{
    int e = blockIdx.x * 256 + threadIdx.x;
    if (e >= N_EDGES) return;
    int row = edge_index[e];
    int col = edge_index[N_EDGES + e];
    int pos = atomicAdd(&cursor[row], 1);
    rows_sorted[pos] = row;
    const int2* ps = (const int2*)(nfh + (size_t)row * 12);
    const int2* pd = (const int2*)(nfh + (size_t)col * 12);
    int2 s0 = ps[0], s1 = ps[1], s2 = ps[2];
    int2 d0 = pd[0], d1 = pd[1], d2 = pd[2];
    float4 a4 = ((const float4*)edge_attr)[e];
    union { _Float16 h[4]; int2 v; } u;
    u.h[0] = (_Float16)a4.x; u.h[1] = (_Float16)a4.y;
    u.h[2] = (_Float16)a4.z; u.h[3] = (_Float16)a4.w;
    int2* op = (int2*)(Asort + (size_t)pos * ASP);
    op[0] = s0; op[1] = s1; op[2] = s2;
    op[3] = d0; op[4] = d1; op[5] = d2;
    op[6] = u.v; op[7] = make_int2(0, 0);
}

// Tier-2: classic permute (perm only).
__global__ __launch_bounds__(256)
void permute_kernel(const int* __restrict__ edge_index, int* cursor, int* perm) {
    int e = blockIdx.x * 256 + threadIdx.x;
    if (e < N_EDGES) {
        int pos = atomicAdd(&cursor[edge_index[e]], 1);
        perm[pos] = e;
    }
}

// ---------------------------------------------------------------------------
// Edge MLP: persistent, barrier-free, weights in registers, bias-in-C.
// ---------------------------------------------------------------------------
#define E_ARENA_SZ 8448   // Hs@0 (4352) / ef@0 (8384, overlays Hs) / rows@8384 (64)

__global__ __launch_bounds__(256, 2)
void edge_mfma_kernel(const _Float16* __restrict__ Asort,
                      const int*   __restrict__ rows_sorted,
                      const _Float16* __restrict__ w1h,
                      const float* __restrict__ eb1,
                      const _Float16* __restrict__ w2h,
                      const float* __restrict__ eb2,
                      float* agg)   // [N_NODES][H_NF]
{
    __shared__ __align__(16) char smem[4 * E_ARENA_SZ];
    int t = threadIdx.x;
    int wv = t >> 6, lane = t & 63;
    char* arena = smem + wv * E_ARENA_SZ;
    _Float16* Hs   = (_Float16*)arena;
    float*    efS  = (float*)arena;          // overlays Hs (same-wave in-order LDS)
    int*      rowsS = (int*)(arena + 8384);
    int m = lane & 15, quad = lane >> 4;

    // loop-invariant weight fragments -> registers
    half8 w1f[8], w2f[8][4];
    #pragma unroll
    for (int tile = 0; tile < 8; ++tile)
        w1f[tile] = *(const half8*)(w1h + (tile * 16 + m) * K1P + quad * 8);
    #pragma unroll
    for (int tile = 0; tile < 8; ++tile)
        #pragma unroll
        for (int ks = 0; ks < 4; ++ks)
            w2f[tile][ks] = *(const half8*)(w2h + (tile * 16 + m) * K2P + ks * 32 + quad * 8);
    float b1v[8], b2v[8];
    #pragma unroll
    for (int tile = 0; tile < 8; ++tile) {
        b1v[tile] = eb1[tile * 16 + m];
        b2v[tile] = eb2[tile * 16 + m];
    }

    const int nwin = N_EDGES / 16;           // 100000
    const int STRIDE = gridDim.x * 4;
    int win = blockIdx.x * 4 + wv;
    if (win >= nwin) return;

    half8 a1 = *(const half8*)(Asort + (size_t)win * (16 * ASP) + m * ASP + quad * 8);
    int rs = (quad == 3) ? rows_sorted[win * 16 + m] : 0;

    while (true) {
        int next = win + STRIDE;
        bool hn = next < nwin;
        if (quad == 3) rowsS[m] = rs;        // publish current rows (same-wave order)
        half8 a1n = {};
        int rsn = 0;
        if (hn) {                            // prefetch next window
            a1n = *(const half8*)(Asort + (size_t)next * (16 * ASP) + m * ASP + quad * 8);
            if (quad == 3) rsn = rows_sorted[next * 16 + m];
        }

        // ---- layer 1: 26(pad32) -> 128, bias in C ----
        #pragma unroll
        for (int tile = 0; tile < 8; ++tile) {
            floatx4 c = {b1v[tile], b1v[tile], b1v[tile], b1v[tile]};
            c = __builtin_amdgcn_mfma_f32_16x16x32_f16(a1, w1f[tile], c, 0, 0, 0);
            int n = tile * 16 + m;
            #pragma unroll
            for (int r = 0; r < 4; ++r)
                Hs[(quad * 4 + r) * K2P + n] = (_Float16)fmaxf(c[r], 0.f);
        }

        // ---- layer 2 A-frags ----
        half8 a2[4];
        #pragma unroll
        for (int ks = 0; ks < 4; ++ks)
            a2[ks] = *(const half8*)(Hs + m * K2P + ks * 32 + quad * 8);

        // ---- layer 2: 128 -> 128, bias in C, write ef ----
        #pragma unroll
        for (int tile = 0; tile < 8; ++tile) {
            floatx4 c = {b2v[tile], b2v[tile], b2v[tile], b2v[tile]};
            #pragma unroll
            for (int ks = 0; ks < 4; ++ks)
                c = __builtin_amdgcn_mfma_f32_16x16x32_f16(a2[ks], w2f[tile][ks], c, 0, 0, 0);
            #pragma unroll
            for (int r = 0; r < 4; ++r)
                efS[(quad * 4 + r) * EFP + tile * 16 + m] = fmaxf(c[r], 0.f);
        }

        // ---- segmented reduction over 16 sorted edges; 2 features/lane ----
        int f = lane;
        int cur = rowsS[0];
        float acc0 = efS[f], acc1 = efS[64 + f];
        #pragma unroll 1
        for (int i = 1; i < 16; ++i) {
            int r = rowsS[i];                       // wave-uniform
            float v0 = efS[i * EFP + f];
            float v1 = efS[i * EFP + 64 + f];
            if (r != cur) {                         // wave-uniform branch
                unsafeAtomicAdd(&agg[(size_t)cur * H_NF + f], acc0);
                unsafeAtomicAdd(&agg[(size_t)cur * H_NF + 64 + f], acc1);
                acc0 = v0; acc1 = v1; cur = r;
            } else { acc0 += v0; acc1 += v1; }
        }
        unsafeAtomicAdd(&agg[(size_t)cur * H_NF + f], acc0);
        unsafeAtomicAdd(&agg[(size_t)cur * H_NF + 64 + f], acc1);

        if (!hn) break;
        win = next; a1 = a1n; rs = rsn;
    }
}

// ---------------------------------------------------------------------------
// Tier-2 edge kernel: in-kernel gather via perm (no Asort).
// ---------------------------------------------------------------------------
#define G_W1      0
#define G_W2      10240
#define G_ARENA   45056
#define G_ARENA_SZ 8448
#define G_TOTAL   (G_ARENA + 4 * G_ARENA_SZ)

__global__ __launch_bounds__(256, 2)
void edge_mfma_gather_kernel(const _Float16* __restrict__ nfh,
                             const int*   __restrict__ edge_index,
                             const float* __restrict__ edge_attr,
                             const _Float16* __restrict__ w1h,
                             const float* __restrict__ eb1,
                             const _Float16* __restrict__ w2h,
                             const float* __restrict__ eb2,
                             const int*   __restrict__ perm,
                             float* agg)
{
    __shared__ __align__(16) char smem[G_TOTAL];
    _Float16* W1s = (_Float16*)(smem + G_W1);
    _Float16* W2s = (_Float16*)(smem + G_W2);
    int t = threadIdx.x;
    {
        const float4* g1 = (const float4*)w1h;
        float4* s1 = (float4*)W1s;
        for (int i = t; i < 640; i += 256) s1[i] = g1[i];
        const float4* g2 = (const float4*)w2h;
        float4* s2 = (float4*)W2s;
        for (int i = t; i < 2176; i += 256) s2[i] = g2[i];
    }
    __syncthreads();

    int wv = t >> 6, lane = t & 63;
    char* arena = smem + G_ARENA + wv * G_ARENA_SZ;
    _Float16* Ain  = (_Float16*)arena;
    _Float16* Hs   = (_Float16*)(arena + 1280);
    float*    efS  = (float*)arena;
    int*      rowsS = (int*)(arena + 8384);

    int m = lane & 15, quad = lane >> 4;
    int el = lane & 15, grp = lane >> 4;
    _Float16* arow = Ain + el * K1P;

    float b1v[8], b2v[8];
    #pragma unroll
    for (int tile = 0; tile < 8; ++tile) {
        b1v[tile] = eb1[tile * 16 + m];
        b2v[tile] = eb2[tile * 16 + m];
    }

    const int nwin = N_EDGES / 16;
    for (int win = blockIdx.x * 4 + wv; win < nwin; win += gridDim.x * 4) {
        int e = perm[win * 16 + el];
        if (grp < 2) {
            int node = edge_index[grp * N_EDGES + e];
            const int2* p = (const int2*)(nfh + (size_t)node * 12);
            int2 x0 = p[0], x1 = p[1], x2 = p[2];
            char* dst = (char*)(arow + grp * 12);
            *(int2*)(dst) = x0; *(int2*)(dst + 8) = x1; *(int2*)(dst + 16) = x2;
        } else if (grp == 2) {
            float4 a4 = ((const float4*)edge_attr)[e];
            arow[24] = (_Float16)a4.x; arow[25] = (_Float16)a4.y;
            arow[26] = (_Float16)a4.z; arow[27] = (_Float16)a4.w;
        } else {
            rowsS[el] = edge_index[e];
            *(int2*)((char*)arow + 56) = make_int2(0, 0);
        }

        half8 a1 = *(const half8*)(Ain + m * K1P + quad * 8);
        #pragma unroll
        for (int tile = 0; tile < 8; ++tile) {
            half8 b = *(const half8*)(W1s + (tile * 16 + m) * K1P + quad * 8);
            floatx4 c = {b1v[tile], b1v[tile], b1v[tile], b1v[tile]};
            c = __builtin_amdgcn_mfma_f32_16x16x32_f16(a1, b, c, 0, 0, 0);
            int n = tile * 16 + m;
            #pragma unroll
            for (int r = 0; r < 4; ++r)
                Hs[(quad * 4 + r) * K2P + n] = (_Float16)fmaxf(c[r], 0.f);
        }
        half8 a2[4];
        #pragma unroll
        for (int ks = 0; ks < 4; ++ks)
            a2[ks] = *(const half8*)(Hs + m * K2P + ks * 32 + quad * 8);
        #pragma unroll
        for (int tile = 0; tile < 8; ++tile) {
            floatx4 c = {b2v[tile], b2v[tile], b2v[tile], b2v[tile]};
            #pragma unroll
            for (int ks = 0; ks < 4; ++ks) {
                half8 b = *(const half8*)(W2s + (tile * 16 + m) * K2P + ks * 32 + quad * 8);
                c = __builtin_amdgcn_mfma_f32_16x16x32_f16(a2[ks], b, c, 0, 0, 0);
            }
            #pragma unroll
            for (int r = 0; r < 4; ++r)
                efS[(quad * 4 + r) * EFP + tile * 16 + m] = fmaxf(c[r], 0.f);
        }

        int f = lane;
        int cur = rowsS[0];
        float acc0 = efS[f], acc1 = efS[64 + f];
        #pragma unroll 1
        for (int i = 1; i < 16; ++i) {
            int r = rowsS[i];
            float v0 = efS[i * EFP + f];
            float v1 = efS[i * EFP + 64 + f];
            if (r != cur) {
                unsafeAtomicAdd(&agg[(size_t)cur * H_NF + f], acc0);
                unsafeAtomicAdd(&agg[(size_t)cur * H_NF + 64 + f], acc1);
                acc0 = v0; acc1 = v1; cur = r;
            } else { acc0 += v0; acc1 += v1; }
        }
        unsafeAtomicAdd(&agg[(size_t)cur * H_NF + f], acc0);
        unsafeAtomicAdd(&agg[(size_t)cur * H_NF + 64 + f], acc1);
    }
}

// ---------------------------------------------------------------------------
// Fused node pipeline, persistent, bias-in-C.
// ---------------------------------------------------------------------------
#define N_W1    0                         // 128*160*2 = 40960
#define N_W23   40960                     // 16*136*2  = 4352 -> 45312
#define N_HS    45312                     // + 4*4352 -> 62720

__global__ __launch_bounds__(256, 2)
void node_mfma_kernel(const float* __restrict__ node_feats,
                      const float* __restrict__ agg,
                      const _Float16* __restrict__ w1nh,
                      const float* __restrict__ nb1,
                      const _Float16* __restrict__ w23h,
                      const float* __restrict__ b23,
                      float* __restrict__ out)
{
    __shared__ __align__(16) char smem[N_HS + 4 * 4352];
    _Float16* W1N  = (_Float16*)(smem + N_W1);
    _Float16* W23s = (_Float16*)(smem + N_W23);
    int t = threadIdx.x;
    {
        const float4* g1 = (const float4*)w1nh;
        float4* s1 = (float4*)W1N;
        for (int i = t; i < 2560; i += 256) s1[i] = g1[i];
        const float4* g2 = (const float4*)w23h;
        float4* s2 = (float4*)W23s;
        for (int i = t; i < 272; i += 256) s2[i] = g2[i];
    }
    __syncthreads();

    int wv = t >> 6, lane = t & 63;
    int m = lane & 15, quad = lane >> 4;
    _Float16* HsW = (_Float16*)(smem + N_HS + wv * 4352);
    const int ntile = (N_NODES + 63) / 64;   // 1563

    float nb1v[8];
    #pragma unroll
    for (int tile = 0; tile < 8; ++tile) nb1v[tile] = nb1[tile * 16 + m];
    float b23v = (m < 4) ? b23[m] : 0.f;

    for (int ti = blockIdx.x; ti < ntile; ti += gridDim.x) {
        int nb = (ti * 4 + wv) * 16;
        if (nb >= N_NODES) continue;
        int nodeA = nb + m;
        if (nodeA >= N_NODES) nodeA = N_NODES - 1;
        const float* ag  = agg + (size_t)nodeA * H_NF;
        const float* nfp = node_feats + (size_t)nodeA * NODE_NF;

        half8 afr[5];
        if (quad == 0) {
            half8 r;
            #pragma unroll
            for (int j = 0; j < 8; ++j) r[j] = (_Float16)nfp[j];
            afr[0] = r;
            afr[4] = load8f(ag + 116);
        } else if (quad == 1) {
            half8 r;
            r[0] = (_Float16)nfp[8]; r[1] = (_Float16)nfp[9];
            r[2] = (_Float16)nfp[10]; r[3] = (_Float16)0.f;
            float4 x = *(const float4*)(ag);
            r[4] = (_Float16)x.x; r[5] = (_Float16)x.y;
            r[6] = (_Float16)x.z; r[7] = (_Float16)x.w;
            afr[0] = r;
            float4 y = *(const float4*)(ag + 124);
            half8 s = zero8();
            s[0] = (_Float16)y.x; s[1] = (_Float16)y.y;
            s[2] = (_Float16)y.z; s[3] = (_Float16)y.w;
            afr[4] = s;
        } else if (quad == 2) {
            afr[0] = load8f(ag + 4);
            afr[4] = zero8();
        } else {
            afr[0] = load8f(ag + 12);
            afr[4] = zero8();
        }
        afr[1] = load8f(ag + 20 + 8 * quad);
        afr[2] = load8f(ag + 52 + 8 * quad);
        afr[3] = load8f(ag + 84 + 8 * quad);

        #pragma unroll
        for (int tile = 0; tile < 8; ++tile) {
            floatx4 c = {nb1v[tile], nb1v[tile], nb1v[tile], nb1v[tile]};
            #pragma unroll
            for (int ks = 0; ks < 5; ++ks) {
                half8 b = *(const half8*)(W1N + (tile * 16 + m) * K1N + ks * 32 + quad * 8);
                c = __builtin_amdgcn_mfma_f32_16x16x32_f16(afr[ks], b, c, 0, 0, 0);
            }
            #pragma unroll
            for (int r = 0; r < 4; ++r)
                HsW[(quad * 4 + r) * K2P + tile * 16 + m] = (_Float16)fmaxf(c[r], 0.f);
        }

        half8 a2[4];
        #pragma unroll
        for (int ks = 0; ks < 4; ++ks)
            a2[ks] = *(const half8*)(HsW + m * K2P + ks * 32 + quad * 8);
        floatx4 c23 = {b23v, b23v, b23v, b23v};
        #pragma unroll
        for (int ks = 0; ks < 4; ++ks) {
            half8 b = *(const half8*)(W23s + m * K2P + ks * 32 + quad * 8);
            c23 = __builtin_amdgcn_mfma_f32_16x16x32_f16(a2[ks], b, c23, 0, 0, 0);
        }
        if (m < 4) {
            #pragma unroll
            for (int r = 0; r < 4; ++r) {
                int node = nb + quad * 4 + r;
                if (node < N_NODES) out[node * 4 + m] = c23[r];
            }
        }
    }
}

// ---------------------------------------------------------------------------
// Tier-3 fp32 fallback.
// ---------------------------------------------------------------------------
__global__ __launch_bounds__(256)
void edge_kernel_atomic(const float* __restrict__ node_feats,
                        const int*   __restrict__ edge_index,
                        const float* __restrict__ edge_attr,
                        const float* __restrict__ eW1,
                        const float* __restrict__ eb1,
                        const float* __restrict__ W2T,
                        const float* __restrict__ eb2,
                        float* agg)
{
    int e = blockIdx.x * 256 + threadIdx.x;
    if (e >= N_EDGES) return;
    int row = edge_index[e];
    int col = edge_index[N_EDGES + e];
    float h[H_NF];
    #pragma unroll
    for (int j = 0; j < H_NF; ++j) h[j] = eb1[j];
    const float* srcp = node_feats + (size_t)row * NODE_NF;
    #pragma unroll 1
    for (int k = 0; k < NODE_NF; ++k) {
        float x = srcp[k];
        const float* w = eW1 + k * H_NF;
        #pragma unroll
        for (int j = 0; j < H_NF; ++j) h[j] = fmaf(x, w[j], h[j]);
    }
    const float* dstp = node_feats + (size_t)col * NODE_NF;
    #pragma unroll 1
    for (int k = 0; k < NODE_NF; ++k) {
        float x = dstp[k];
        const float* w = eW1 + (NODE_NF + k) * H_NF;
        #pragma unroll
        for (int j = 0; j < H_NF; ++j) h[j] = fmaf(x, w[j], h[j]);
    }
    float4 at = ((const float4*)edge_attr)[e];
    float av[EDGE_NF] = {at.x, at.y, at.z, at.w};
    #pragma unroll
    for (int k = 0; k < EDGE_NF; ++k) {
        float x = av[k];
        const float* w = eW1 + (2 * NODE_NF + k) * H_NF;
        #pragma unroll
        for (int j = 0; j < H_NF; ++j) h[j] = fmaf(x, w[j], h[j]);
    }
    #pragma unroll
    for (int j = 0; j < H_NF; ++j) h[j] = fmaxf(h[j], 0.f);
    #pragma unroll 1
    for (int j0 = 0; j0 < H_NF; j0 += 8) {
        float acc[8];
        #pragma unroll
        for (int jj = 0; jj < 8; ++jj) acc[jj] = eb2[j0 + jj];
        #pragma unroll
        for (int k = 0; k < H_NF; ++k) {
            float x = h[k];
            #pragma unroll
            for (int jj = 0; jj < 8; ++jj)
                acc[jj] = fmaf(x, W2T[(j0 + jj) * H_NF + k], acc[jj]);
        }
        #pragma unroll
        for (int jj = 0; jj < 8; ++jj)
            unsafeAtomicAdd(&agg[(size_t)row * H_NF + j0 + jj], fmaxf(acc[jj], 0.f));
    }
}

__global__ __launch_bounds__(256)
void node_kernel1(const float* __restrict__ node_feats, float* agg_nh,
                  const float* __restrict__ nW1, const float* __restrict__ nb1)
{
    int n = blockIdx.x * 256 + threadIdx.x;
    if (n >= N_NODES) return;
    float acc[H_NF];
    #pragma unroll
    for (int j = 0; j < H_NF; ++j) acc[j] = nb1[j];
    const float* nfp = node_feats + (size_t)n * NODE_NF;
    #pragma unroll 1
    for (int k = 0; k < NODE_NF; ++k) {
        float x = nfp[k];
        const float* w = nW1 + k * H_NF;
        #pragma unroll
        for (int j = 0; j < H_NF; ++j) acc[j] = fmaf(x, w[j], acc[j]);
    }
    const float4* ap = (const float4*)(agg_nh + (size_t)n * H_NF);
    #pragma unroll 1
    for (int k4 = 0; k4 < H_NF / 4; ++k4) {
        float4 x = ap[k4];
        const float* w0 = nW1 + (NODE_NF + k4 * 4 + 0) * H_NF;
        const float* w1 = nW1 + (NODE_NF + k4 * 4 + 1) * H_NF;
        const float* w2 = nW1 + (NODE_NF + k4 * 4 + 2) * H_NF;
        const float* w3 = nW1 + (NODE_NF + k4 * 4 + 3) * H_NF;
        #pragma unroll
        for (int j = 0; j < H_NF; ++j) {
            acc[j] = fmaf(x.x, w0[j], acc[j]);
            acc[j] = fmaf(x.y, w1[j], acc[j]);
            acc[j] = fmaf(x.z, w2[j], acc[j]);
            acc[j] = fmaf(x.w, w3[j], acc[j]);
        }
    }
    float* op = agg_nh + (size_t)n * H_NF;
    #pragma unroll
    for (int j4 = 0; j4 < H_NF / 4; ++j4) {
        float4 o = make_float4(fmaxf(acc[j4*4+0], 0.f), fmaxf(acc[j4*4+1], 0.f),
                               fmaxf(acc[j4*4+2], 0.f), fmaxf(acc[j4*4+3], 0.f));
        ((float4*)op)[j4] = o;
    }
}

__global__ __launch_bounds__(256)
void node_kernel2(const float* __restrict__ nh, const float* __restrict__ nW2,
                  const float* __restrict__ nb2, const float* __restrict__ fW,
                  const float* __restrict__ fb, float* __restrict__ out)
{
    int n = blockIdx.x * 256 + threadIdx.x;
    if (n >= N_NODES) return;
    float acc[H_NF];
    #pragma unroll
    for (int j = 0; j < H_NF; ++j) acc[j] = nb2[j];
    const float4* hp = (const float4*)(nh + (size_t)n * H_NF);
    #pragma unroll 1
    for (int k4 = 0; k4 < H_NF / 4; ++k4) {
        float4 x = hp[k4];
        const float* w0 = nW2 + (k4 * 4 + 0) * H_NF;
        const float* w1 = nW2 + (k4 * 4 + 1) * H_NF;
        const float* w2 = nW2 + (k4 * 4 + 2) * H_NF;
        const float* w3 = nW2 + (k4 * 4 + 3) * H_NF;
        #pragma unroll
        for (int j = 0; j < H_NF; ++j) {
            acc[j] = fmaf(x.x, w0[j], acc[j]);
            acc[j] = fmaf(x.y, w1[j], acc[j]);
            acc[j] = fmaf(x.z, w2[j], acc[j]);
            acc[j] = fmaf(x.w, w3[j], acc[j]);
        }
    }
    float o0 = fb[0], o1 = fb[1], o2 = fb[2], o3 = fb[3];
    #pragma unroll
    for (int j = 0; j < H_NF; ++j) {
        o0 = fmaf(acc[j], fW[j * 4 + 0], o0);
        o1 = fmaf(acc[j], fW[j * 4 + 1], o1);
        o2 = fmaf(acc[j], fW[j * 4 + 2], o2);
        o3 = fmaf(acc[j], fW[j * 4 + 3], o3);
    }
    ((float4*)out)[n] = make_float4(o0, o1, o2, o3);
}

extern "C" void kernel_launch(void* const* d_in, const int* in_sizes, int n_in,
                              void* d_out, int out_size, void* d_ws, size_t ws_size,
                              hipStream_t stream)
{
    const float* node_feats = (const float*)d_in[0];
    const int*   edge_index = (const int*)d_in[1];
    const float* edge_attr  = (const float*)d_in[2];
    const float* eW1 = (const float*)d_in[3];
    const float* eb1 = (const float*)d_in[4];
    const float* eW2 = (const float*)d_in[5];
    const float* eb2 = (const float*)d_in[6];
    const float* nW1 = (const float*)d_in[7];
    const float* nb1 = (const float*)d_in[8];
    const float* nW2 = (const float*)d_in[9];
    const float* nb2 = (const float*)d_in[10];
    const float* fW  = (const float*)d_in[11];
    const float* fb  = (const float*)d_in[12];
    float* out = (float*)d_out;

    // ---- workspace carve-up (256B aligned). agg+hist adjacent -> ONE memset.
    size_t off = 0;
    auto carve = [&](size_t bytes) {
        void* p = (char*)d_ws + off;
        off = (off + bytes + 255) & ~(size_t)255;
        return p;
    };
    float*     agg    = (float*)carve((size_t)N_NODES * H_NF * sizeof(float)); // 51.2 MB
    int*       hist   = (int*)  carve((size_t)N_NODES * sizeof(int));
    size_t zero_bytes = off;   // agg + hist (contiguous from d_ws base)
    int*       starts = (int*)  carve((size_t)(N_NODES + 1) * sizeof(int));
    int*       cursor = (int*)  carve((size_t)N_NODES * sizeof(int));
    int*       bsum   = (int*)  carve((size_t)(NBLK + 1) * sizeof(int));
    _Float16*  nfh    = (_Float16*)carve((size_t)N_NODES * 12 * sizeof(_Float16)); // 2.4 MB
    _Float16*  w1h    = (_Float16*)carve((size_t)H_NF * K1P * sizeof(_Float16));
    _Float16*  w2h    = (_Float16*)carve((size_t)H_NF * K2P * sizeof(_Float16));
    _Float16*  w1nh   = (_Float16*)carve((size_t)H_NF * K1N * sizeof(_Float16));
    _Float16*  w23h   = (_Float16*)carve((size_t)16 * K2P * sizeof(_Float16));
    float*     b23    = (float*)carve(4 * sizeof(float));
    int*       perm   = (int*)  carve((size_t)N_EDGES * sizeof(int));          // tier-2 only
    size_t required_t2 = off;
    _Float16*  Asort  = (_Float16*)carve((size_t)N_EDGES * ASP * sizeof(_Float16)); // 102.4 MB
    int*       rowsS  = (int*)carve((size_t)N_EDGES * sizeof(int));                 // 6.4 MB
    size_t required_t1 = off;

    if (ws_size >= required_t2) {
        hipMemsetAsync(d_ws, 0, zero_bytes, stream);
        prep_hist_kernel<<<(SEG5 + 255) / 256, 256, 0, stream>>>(
            node_feats, eW1, eW2, nW1, nW2, fW, nb2, fb, edge_index,
            nfh, w1h, w2h, w1nh, w23h, b23, hist);
        scan1_kernel<<<NBLK, SCAN_B, 0, stream>>>(hist, starts, bsum);
        scan2_kernel<<<1, 64, 0, stream>>>(bsum);
        scan3_kernel<<<(N_NODES + 255) / 256, 256, 0, stream>>>(starts, cursor, bsum);

        if (ws_size >= required_t1) {
            permgather_kernel<<<(N_EDGES + 255) / 256, 256, 0, stream>>>(
                edge_index, nfh, edge_attr, cursor, Asort, rowsS);
            edge_mfma_kernel<<<512, 256, 0, stream>>>(
                Asort, rowsS, w1h, eb1, w2h, eb2, agg);
        } else {
            permute_kernel<<<(N_EDGES + 255) / 256, 256, 0, stream>>>(edge_index, cursor, perm);
            edge_mfma_gather_kernel<<<512, 256, 0, stream>>>(
                nfh, edge_index, edge_attr, w1h, eb1, w2h, eb2, perm, agg);
        }
        node_mfma_kernel<<<512, 256, 0, stream>>>(
            node_feats, agg, w1nh, nb1, w23h, b23, out);
    } else {
        // tier 3: fp32 atomic scatter path
        float* agg_fb = (float*)d_ws;
        float* W2T_fb = (float*)((char*)d_ws + (size_t)N_NODES * H_NF * sizeof(float));
        transpose_w2<<<(H_NF * H_NF + 255) / 256, 256, 0, stream>>>(eW2, W2T_fb);
        hipMemsetAsync(agg_fb, 0, (size_t)N_NODES * H_NF * sizeof(float), stream);
        edge_kernel_atomic<<<(N_EDGES + 255) / 256, 256, 0, stream>>>(
            node_feats, edge_index, edge_attr, eW1, eb1, W2T_fb, eb2, agg_fb);
        node_kernel1<<<(N_NODES + 255) / 256, 256, 0, stream>>>(node_feats, agg_fb, nW1, nb1);
        node_kernel2<<<(N_NODES + 255) / 256, 256, 0, stream>>>(agg_fb, nW2, nb2, fW, fb, out);
    }
}

// Round 9
// 474.290 us; speedup vs baseline: 1.2874x; 1.1574x over previous
//
#include <hip/hip_runtime.h>

#define N_NODES 100000
#define N_EDGES 1600000
#define NODE_NF 11
#define EDGE_NF 4
#define H_NF 128
#define SCAN_B 1024
#define NBLK ((N_NODES + SCAN_B - 1) / SCAN_B)   // 98

// Edge-MLP input layout (halves): src@0..10, 0@11, dst@12..22, 0@23,
// attr@24..27, 0@28..31. K=32 MFMA window covers 0..31.
#define ASP 32    // Asort row stride (halves) = 64 B
#define K1P 40    // w1h row stride (halves)
#define K2P 136   // h / w2h row stride (halves)
#define EFP 131   // ef row stride (floats) — tier-2 kernel only
#define K1N 160   // node layer-1 padded K

typedef _Float16 half8 __attribute__((ext_vector_type(8)));
typedef float floatx4 __attribute__((ext_vector_type(4)));

__device__ inline half8 load8f(const float* p) {
    float4 x0 = *(const float4*)(p);
    float4 x1 = *(const float4*)(p + 4);
    half8 r;
    r[0]=(_Float16)x0.x; r[1]=(_Float16)x0.y; r[2]=(_Float16)x0.z; r[3]=(_Float16)x0.w;
    r[4]=(_Float16)x1.x; r[5]=(_Float16)x1.y; r[6]=(_Float16)x1.z; r[7]=(_Float16)x1.w;
    return r;
}
__device__ inline half8 zero8() {
    half8 z;
    #pragma unroll
    for (int j = 0; j < 8; ++j) z[j] = (_Float16)0.f;
    return z;
}

// ---------------------------------------------------------------------------
// Fused prep + hist (one launch, flat-index segments).
// ---------------------------------------------------------------------------
#define SEG0 (N_NODES * 12)            // nfh
#define SEG1 (SEG0 + H_NF * K1P)       // w1h
#define SEG2 (SEG1 + H_NF * K2P)       // w2h
#define SEG3 (SEG2 + H_NF * K1N)       // w1nh
#define SEG4 (SEG3 + 16 * K2P + 4)     // w23h + b23
#define SEG5 (SEG4 + N_EDGES)          // hist

__global__ __launch_bounds__(256)
void prep_hist_kernel(const float* __restrict__ nf,
                      const float* __restrict__ eW1,
                      const float* __restrict__ eW2,
                      const float* __restrict__ nW1,
                      const float* __restrict__ nW2,
                      const float* __restrict__ fW,
                      const float* __restrict__ nb2,
                      const float* __restrict__ fb,
                      const int*   __restrict__ edge_index,
                      _Float16* __restrict__ nfh,
                      _Float16* __restrict__ w1h,
                      _Float16* __restrict__ w2h,
                      _Float16* __restrict__ w1nh,
                      _Float16* __restrict__ w23h,
                      float* __restrict__ b23,
                      int* hist)
{
    int i = blockIdx.x * 256 + threadIdx.x;
    if (i < SEG0) {
        int n = i / 12, k = i - n * 12;
        nfh[i] = (k < NODE_NF) ? (_Float16)nf[(size_t)n * NODE_NF + k] : (_Float16)0.f;
    } else if (i < SEG1) {
        int j = i - SEG0;
        int n = j / K1P, k = j - n * K1P;
        float v = 0.f;
        if (k < 11)                 v = eW1[k * H_NF + n];
        else if (k >= 12 && k < 23) v = eW1[(k - 1) * H_NF + n];
        else if (k >= 24 && k < 28) v = eW1[(k - 2) * H_NF + n];
        w1h[j] = (_Float16)v;
    } else if (i < SEG2) {
        int j = i - SEG1;
        int n = j / K2P, k = j - n * K2P;
        w2h[j] = (k < H_NF) ? (_Float16)eW2[k * H_NF + n] : (_Float16)0.f;
    } else if (i < SEG3) {
        int j = i - SEG2;
        int n = j / K1N, k = j - n * K1N;
        float v = 0.f;
        if (k < 11)                  v = nW1[k * H_NF + n];
        else if (k >= 12 && k < 140) v = nW1[(k - 1) * H_NF + n];
        w1nh[j] = (_Float16)v;
    } else if (i < SEG4) {
        int j = i - SEG3;
        if (j < 16 * K2P) {
            int n = j / K2P, k = j - n * K2P;
            float v = 0.f;
            if (n < 4 && k < H_NF) {
                for (int q = 0; q < H_NF; ++q) v += nW2[k * H_NF + q] * fW[q * 4 + n];
            }
            w23h[j] = (_Float16)v;
        } else {
            int o = j - 16 * K2P;
            float v = fb[o];
            for (int q = 0; q < H_NF; ++q) v += nb2[q] * fW[q * 4 + o];
            b23[o] = v;
        }
    } else if (i < SEG5) {
        int e = i - SEG4;
        atomicAdd(&hist[edge_index[e]], 1);
    }
}

__global__ __launch_bounds__(256)
void transpose_w2(const float* __restrict__ W, float* __restrict__ WT) {
    int i = blockIdx.x * 256 + threadIdx.x;
    if (i < H_NF * H_NF) {
        int k = i >> 7, j = i & (H_NF - 1);
        WT[j * H_NF + k] = W[i];
    }
}

// ---------------------------------------------------------------------------
// Scan chain.
// ---------------------------------------------------------------------------
__global__ __launch_bounds__(SCAN_B)
void scan1_kernel(const int* __restrict__ hist, int* starts, int* bsum) {
    __shared__ int buf[SCAN_B];
    int i = blockIdx.x * SCAN_B + threadIdx.x;
    int v = (i < N_NODES) ? hist[i] : 0;
    buf[threadIdx.x] = v;
    __syncthreads();
    for (int off = 1; off < SCAN_B; off <<= 1) {
        int t = (threadIdx.x >= off) ? buf[threadIdx.x - off] : 0;
        __syncthreads();
        buf[threadIdx.x] += t;
        __syncthreads();
    }
    if (i < N_NODES) starts[i] = buf[threadIdx.x] - v;
    if (threadIdx.x == SCAN_B - 1) bsum[blockIdx.x] = buf[SCAN_B - 1];
}

__global__ void scan2_kernel(int* bsum) {
    if (threadIdx.x == 0 && blockIdx.x == 0) {
        int run = 0;
        for (int b = 0; b < NBLK; ++b) { int t = bsum[b]; bsum[b] = run; run += t; }
        bsum[NBLK] = run;
    }
}

__global__ __launch_bounds__(256)
void scan3_kernel(int* starts, int* cursor, const int* __restrict__ bsum) {
    int i = blockIdx.x * 256 + threadIdx.x;
    if (i < N_NODES) {
        int s = starts[i] + bsum[i / SCAN_B];
        starts[i] = s;
        cursor[i] = s;
    }
    if (i == 0) starts[N_NODES] = bsum[NBLK];
}

// ---------------------------------------------------------------------------
// Fused permute + gather: sorted position + MFMA-ready A row in one pass.
// ---------------------------------------------------------------------------
__global__ __launch_bounds__(256)
void permgather_kernel(const int* __restrict__ edge_index,
                       const _Float16* __restrict__ nfh,
                       const float* __restrict__ edge_attr,
                       int* cursor,
                       _Float16* __restrict__ Asort,
                       int* __restrict__ rows_sorted)
{
    int e = blockIdx.x * 256 + threadIdx.x;
    if (e >= N_EDGES) return;
    int row = edge_index[e];
    int col = edge_index[N_EDGES + e];
    int pos = atomicAdd(&cursor[row], 1);
    rows_sorted[pos] = row;
    const int2* ps = (const int2*)(nfh + (size_t)row * 12);
    const int2* pd = (const int2*)(nfh + (size_t)col * 12);
    int2 s0 = ps[0], s1 = ps[1], s2 = ps[2];
    int2 d0 = pd[0], d1 = pd[1], d2 = pd[2];
    float4 a4 = ((const float4*)edge_attr)[e];
    union { _Float16 h[4]; int2 v; } u;
    u.h[0] = (_Float16)a4.x; u.h[1] = (_Float16)a4.y;
    u.h[2] = (_Float16)a4.z; u.h[3] = (_Float16)a4.w;
    int2* op = (int2*)(Asort + (size_t)pos * ASP);
    op[0] = s0; op[1] = s1; op[2] = s2;
    op[3] = d0; op[4] = d1; op[5] = d2;
    op[6] = u.v; op[7] = make_int2(0, 0);
}

// Tier-2: classic permute (perm only).
__global__ __launch_bounds__(256)
void permute_kernel(const int* __restrict__ edge_index, int* cursor, int* perm) {
    int e = blockIdx.x * 256 + threadIdx.x;
    if (e < N_EDGES) {
        int pos = atomicAdd(&cursor[edge_index[e]], 1);
        perm[pos] = e;
    }
}

// ---------------------------------------------------------------------------
// Edge MLP v4: persistent, barrier-free, weights in registers, epilogue bias
// (bias-in-C reverted — R8 showed it regresses), and a C-LAYOUT register/
// shuffle segmented reduction: no ef LDS tile, no serial LDS-latency loop.
// Per window: ballot boundary mask (avg ~2 segments at mean degree 16) ->
// per-segment in-lane predicated adds + 2x shfl_xor -> quad-0 atomics.
// ---------------------------------------------------------------------------
#define E_ARENA_SZ 4480   // Hs@0 (4352 B) + rows@4352 (64 B) + pad

__global__ __launch_bounds__(256, 2)
void edge_mfma_kernel(const _Float16* __restrict__ Asort,
                      const int*   __restrict__ rows_sorted,
                      const _Float16* __restrict__ w1h,
                      const float* __restrict__ eb1,
                      const _Float16* __restrict__ w2h,
                      const float* __restrict__ eb2,
                      float* agg)   // [N_NODES][H_NF]
{
    __shared__ __align__(16) char smem[4 * E_ARENA_SZ];
    int t = threadIdx.x;
    int wv = t >> 6, lane = t & 63;
    char* arena = smem + wv * E_ARENA_SZ;
    _Float16* Hs = (_Float16*)arena;
    int* rowsS = (int*)(arena + 4352);
    int m = lane & 15, quad = lane >> 4;

    // loop-invariant weight fragments -> registers
    half8 w1f[8], w2f[8][4];
    #pragma unroll
    for (int tile = 0; tile < 8; ++tile)
        w1f[tile] = *(const half8*)(w1h + (tile * 16 + m) * K1P + quad * 8);
    #pragma unroll
    for (int tile = 0; tile < 8; ++tile)
        #pragma unroll
        for (int ks = 0; ks < 4; ++ks)
            w2f[tile][ks] = *(const half8*)(w2h + (tile * 16 + m) * K2P + ks * 32 + quad * 8);
    float b1v[8], b2v[8];
    #pragma unroll
    for (int tile = 0; tile < 8; ++tile) {
        b1v[tile] = eb1[tile * 16 + m];
        b2v[tile] = eb2[tile * 16 + m];
    }

    const int nwin = N_EDGES / 16;           // 100000
    const int STRIDE = gridDim.x * 4;
    int win = blockIdx.x * 4 + wv;
    if (win >= nwin) return;

    half8 a1 = *(const half8*)(Asort + (size_t)win * (16 * ASP) + m * ASP + quad * 8);
    int rs = (quad == 3) ? rows_sorted[win * 16 + m] : 0;

    while (true) {
        int next = win + STRIDE;
        bool hn = next < nwin;
        if (quad == 3) rowsS[m] = rs;        // publish rows (same-wave in-order LDS)
        half8 a1n = {};
        int rsn = 0;
        if (hn) {                            // prefetch next window
            a1n = *(const half8*)(Asort + (size_t)next * (16 * ASP) + m * ASP + quad * 8);
            if (quad == 3) rsn = rows_sorted[next * 16 + m];
        }

        // ---- layer 1: 26(pad32) -> 128, epilogue bias+relu ----
        #pragma unroll
        for (int tile = 0; tile < 8; ++tile) {
            floatx4 c = {0.f, 0.f, 0.f, 0.f};
            c = __builtin_amdgcn_mfma_f32_16x16x32_f16(a1, w1f[tile], c, 0, 0, 0);
            int n = tile * 16 + m;
            #pragma unroll
            for (int r = 0; r < 4; ++r)
                Hs[(quad * 4 + r) * K2P + n] = (_Float16)fmaxf(c[r] + b1v[tile], 0.f);
        }

        // ---- layer 2 A-frags ----
        half8 a2[4];
        #pragma unroll
        for (int ks = 0; ks < 4; ++ks)
            a2[ks] = *(const half8*)(Hs + m * K2P + ks * 32 + quad * 8);

        // ---- layer 2: 128 -> 128, values stay in registers (C-layout) ----
        // vals[tile*4+r] = ef[edge = quad*4+r][feature = tile*16+m]
        float vals[32];
        #pragma unroll
        for (int tile = 0; tile < 8; ++tile) {
            floatx4 c = {0.f, 0.f, 0.f, 0.f};
            #pragma unroll
            for (int ks = 0; ks < 4; ++ks)
                c = __builtin_amdgcn_mfma_f32_16x16x32_f16(a2[ks], w2f[tile][ks], c, 0, 0, 0);
            #pragma unroll
            for (int r = 0; r < 4; ++r)
                vals[tile * 4 + r] = fmaxf(c[r] + b2v[tile], 0.f);
        }

        // ---- segmented reduction, C-layout (no ef LDS round-trip) ----
        int er0 = rowsS[quad * 4 + 0], er1 = rowsS[quad * 4 + 1];
        int er2 = rowsS[quad * 4 + 2], er3 = rowsS[quad * 4 + 3];
        int li = lane & 15;
        bool bi = (lane < 16) && ((li == 0) || (rowsS[li] != rowsS[li - 1]));
        unsigned long long bm = __ballot(bi);
        unsigned mk = (unsigned)(bm & 0xFFFFull);   // wave-uniform segment-start mask
        while (mk) {
            int start = __builtin_ctz(mk);          // wave-uniform
            mk &= mk - 1;
            int srow = rowsS[start];                // broadcast LDS read
            float s[8];
            #pragma unroll
            for (int tile = 0; tile < 8; ++tile) {
                float v = 0.f;
                if (er0 == srow) v += vals[tile * 4 + 0];
                if (er1 == srow) v += vals[tile * 4 + 1];
                if (er2 == srow) v += vals[tile * 4 + 2];
                if (er3 == srow) v += vals[tile * 4 + 3];
                s[tile] = v;
            }
            #pragma unroll
            for (int tile = 0; tile < 8; ++tile) {
                s[tile] += __shfl_xor(s[tile], 16);
                s[tile] += __shfl_xor(s[tile], 32);
            }
            if (quad == 0) {
                #pragma unroll
                for (int tile = 0; tile < 8; ++tile)
                    unsafeAtomicAdd(&agg[(size_t)srow * H_NF + tile * 16 + m], s[tile]);
            }
        }

        if (!hn) break;
        win = next; a1 = a1n; rs = rsn;
    }
}

// ---------------------------------------------------------------------------
// Tier-2 edge kernel: in-kernel gather via perm (no Asort). LDS reduction.
// ---------------------------------------------------------------------------
#define G_W1      0
#define G_W2      10240
#define G_ARENA   45056
#define G_ARENA_SZ 8448
#define G_TOTAL   (G_ARENA + 4 * G_ARENA_SZ)

__global__ __launch_bounds__(256, 2)
void edge_mfma_gather_kernel(const _Float16* __restrict__ nfh,
                             const int*   __restrict__ edge_index,
                             const float* __restrict__ edge_attr,
                             const _Float16* __restrict__ w1h,
                             const float* __restrict__ eb1,
                             const _Float16* __restrict__ w2h,
                             const float* __restrict__ eb2,
                             const int*   __restrict__ perm,
                             float* agg)
{
    __shared__ __align__(16) char smem[G_TOTAL];
    _Float16* W1s = (_Float16*)(smem + G_W1);
    _Float16* W2s = (_Float16*)(smem + G_W2);
    int t = threadIdx.x;
    {
        const float4* g1 = (const float4*)w1h;
        float4* s1 = (float4*)W1s;
        for (int i = t; i < 640; i += 256) s1[i] = g1[i];
        const float4* g2 = (const float4*)w2h;
        float4* s2 = (float4*)W2s;
        for (int i = t; i < 2176; i += 256) s2[i] = g2[i];
    }
    __syncthreads();

    int wv = t >> 6, lane = t & 63;
    char* arena = smem + G_ARENA + wv * G_ARENA_SZ;
    _Float16* Ain  = (_Float16*)arena;
    _Float16* Hs   = (_Float16*)(arena + 1280);
    float*    efS  = (float*)arena;
    int*      rowsS = (int*)(arena + 8384);

    int m = lane & 15, quad = lane >> 4;
    int el = lane & 15, grp = lane >> 4;
    _Float16* arow = Ain + el * K1P;

    float b1v[8], b2v[8];
    #pragma unroll
    for (int tile = 0; tile < 8; ++tile) {
        b1v[tile] = eb1[tile * 16 + m];
        b2v[tile] = eb2[tile * 16 + m];
    }

    const int nwin = N_EDGES / 16;
    for (int win = blockIdx.x * 4 + wv; win < nwin; win += gridDim.x * 4) {
        int e = perm[win * 16 + el];
        if (grp < 2) {
            int node = edge_index[grp * N_EDGES + e];
            const int2* p = (const int2*)(nfh + (size_t)node * 12);
            int2 x0 = p[0], x1 = p[1], x2 = p[2];
            char* dst = (char*)(arow + grp * 12);
            *(int2*)(dst) = x0; *(int2*)(dst + 8) = x1; *(int2*)(dst + 16) = x2;
        } else if (grp == 2) {
            float4 a4 = ((const float4*)edge_attr)[e];
            arow[24] = (_Float16)a4.x; arow[25] = (_Float16)a4.y;
            arow[26] = (_Float16)a4.z; arow[27] = (_Float16)a4.w;
        } else {
            rowsS[el] = edge_index[e];
            *(int2*)((char*)arow + 56) = make_int2(0, 0);
        }

        half8 a1 = *(const half8*)(Ain + m * K1P + quad * 8);
        #pragma unroll
        for (int tile = 0; tile < 8; ++tile) {
            half8 b = *(const half8*)(W1s + (tile * 16 + m) * K1P + quad * 8);
            floatx4 c = {0.f, 0.f, 0.f, 0.f};
            c = __builtin_amdgcn_mfma_f32_16x16x32_f16(a1, b, c, 0, 0, 0);
            int n = tile * 16 + m;
            #pragma unroll
            for (int r = 0; r < 4; ++r)
                Hs[(quad * 4 + r) * K2P + n] = (_Float16)fmaxf(c[r] + b1v[tile], 0.f);
        }
        half8 a2[4];
        #pragma unroll
        for (int ks = 0; ks < 4; ++ks)
            a2[ks] = *(const half8*)(Hs + m * K2P + ks * 32 + quad * 8);
        #pragma unroll
        for (int tile = 0; tile < 8; ++tile) {
            floatx4 c = {0.f, 0.f, 0.f, 0.f};
            #pragma unroll
            for (int ks = 0; ks < 4; ++ks) {
                half8 b = *(const half8*)(W2s + (tile * 16 + m) * K2P + ks * 32 + quad * 8);
                c = __builtin_amdgcn_mfma_f32_16x16x32_f16(a2[ks], b, c, 0, 0, 0);
            }
            #pragma unroll
            for (int r = 0; r < 4; ++r)
                efS[(quad * 4 + r) * EFP + tile * 16 + m] = fmaxf(c[r] + b2v[tile], 0.f);
        }

        int f = lane;
        int cur = rowsS[0];
        float acc0 = efS[f], acc1 = efS[64 + f];
        #pragma unroll 1
        for (int i = 1; i < 16; ++i) {
            int r = rowsS[i];
            float v0 = efS[i * EFP + f];
            float v1 = efS[i * EFP + 64 + f];
            if (r != cur) {
                unsafeAtomicAdd(&agg[(size_t)cur * H_NF + f], acc0);
                unsafeAtomicAdd(&agg[(size_t)cur * H_NF + 64 + f], acc1);
                acc0 = v0; acc1 = v1; cur = r;
            } else { acc0 += v0; acc1 += v1; }
        }
        unsafeAtomicAdd(&agg[(size_t)cur * H_NF + f], acc0);
        unsafeAtomicAdd(&agg[(size_t)cur * H_NF + 64 + f], acc1);
    }
}

// ---------------------------------------------------------------------------
// Fused node pipeline, persistent, epilogue bias (bias-in-C reverted).
// ---------------------------------------------------------------------------
#define N_W1    0                         // 128*160*2 = 40960
#define N_W23   40960                     // 16*136*2  = 4352 -> 45312
#define N_HS    45312                     // + 4*4352 -> 62720

__global__ __launch_bounds__(256, 2)
void node_mfma_kernel(const float* __restrict__ node_feats,
                      const float* __restrict__ agg,
                      const _Float16* __restrict__ w1nh,
                      const float* __restrict__ nb1,
                      const _Float16* __restrict__ w23h,
                      const float* __restrict__ b23,
                      float* __restrict__ out)
{
    __shared__ __align__(16) char smem[N_HS + 4 * 4352];
    _Float16* W1N  = (_Float16*)(smem + N_W1);
    _Float16* W23s = (_Float16*)(smem + N_W23);
    int t = threadIdx.x;
    {
        const float4* g1 = (const float4*)w1nh;
        float4* s1 = (float4*)W1N;
        for (int i = t; i < 2560; i += 256) s1[i] = g1[i];
        const float4* g2 = (const float4*)w23h;
        float4* s2 = (float4*)W23s;
        for (int i = t; i < 272; i += 256) s2[i] = g2[i];
    }
    __syncthreads();

    int wv = t >> 6, lane = t & 63;
    int m = lane & 15, quad = lane >> 4;
    _Float16* HsW = (_Float16*)(smem + N_HS + wv * 4352);
    const int ntile = (N_NODES + 63) / 64;   // 1563

    float nb1v[8];
    #pragma unroll
    for (int tile = 0; tile < 8; ++tile) nb1v[tile] = nb1[tile * 16 + m];
    float b23v = (m < 4) ? b23[m] : 0.f;

    for (int ti = blockIdx.x; ti < ntile; ti += gridDim.x) {
        int nb = (ti * 4 + wv) * 16;
        if (nb >= N_NODES) continue;
        int nodeA = nb + m;
        if (nodeA >= N_NODES) nodeA = N_NODES - 1;
        const float* ag  = agg + (size_t)nodeA * H_NF;
        const float* nfp = node_feats + (size_t)nodeA * NODE_NF;

        half8 afr[5];
        if (quad == 0) {
            half8 r;
            #pragma unroll
            for (int j = 0; j < 8; ++j) r[j] = (_Float16)nfp[j];
            afr[0] = r;
            afr[4] = load8f(ag + 116);
        } else if (quad == 1) {
            half8 r;
            r[0] = (_Float16)nfp[8]; r[1] = (_Float16)nfp[9];
            r[2] = (_Float16)nfp[10]; r[3] = (_Float16)0.f;
            float4 x = *(const float4*)(ag);
            r[4] = (_Float16)x.x; r[5] = (_Float16)x.y;
            r[6] = (_Float16)x.z; r[7] = (_Float16)x.w;
            afr[0] = r;
            float4 y = *(const float4*)(ag + 124);
            half8 s = zero8();
            s[0] = (_Float16)y.x; s[1] = (_Float16)y.y;
            s[2] = (_Float16)y.z; s[3] = (_Float16)y.w;
            afr[4] = s;
        } else if (quad == 2) {
            afr[0] = load8f(ag + 4);
            afr[4] = zero8();
        } else {
            afr[0] = load8f(ag + 12);
            afr[4] = zero8();
        }
        afr[1] = load8f(ag + 20 + 8 * quad);
        afr[2] = load8f(ag + 52 + 8 * quad);
        afr[3] = load8f(ag + 84 + 8 * quad);

        #pragma unroll
        for (int tile = 0; tile < 8; ++tile) {
            floatx4 c = {0.f, 0.f, 0.f, 0.f};
            #pragma unroll
            for (int ks = 0; ks < 5; ++ks) {
                half8 b = *(const half8*)(W1N + (tile * 16 + m) * K1N + ks * 32 + quad * 8);
                c = __builtin_amdgcn_mfma_f32_16x16x32_f16(afr[ks], b, c, 0, 0, 0);
            }
            #pragma unroll
            for (int r = 0; r < 4; ++r)
                HsW[(quad * 4 + r) * K2P + tile * 16 + m] = (_Float16)fmaxf(c[r] + nb1v[tile], 0.f);
        }

        half8 a2[4];
        #pragma unroll
        for (int ks = 0; ks < 4; ++ks)
            a2[ks] = *(const half8*)(HsW + m * K2P + ks * 32 + quad * 8);
        floatx4 c23 = {0.f, 0.f, 0.f, 0.f};
        #pragma unroll
        for (int ks = 0; ks < 4; ++ks) {
            half8 b = *(const half8*)(W23s + m * K2P + ks * 32 + quad * 8);
            c23 = __builtin_amdgcn_mfma_f32_16x16x32_f16(a2[ks], b, c23, 0, 0, 0);
        }
        if (m < 4) {
            #pragma unroll
            for (int r = 0; r < 4; ++r) {
                int node = nb + quad * 4 + r;
                if (node < N_NODES) out[node * 4 + m] = c23[r] + b23v;
            }
        }
    }
}

// ---------------------------------------------------------------------------
// Tier-3 fp32 fallback.
// ---------------------------------------------------------------------------
__global__ __launch_bounds__(256)
void edge_kernel_atomic(const float* __restrict__ node_feats,
                        const int*   __restrict__ edge_index,
                        const float* __restrict__ edge_attr,
                        const float* __restrict__ eW1,
                        const float* __restrict__ eb1,
                        const float* __restrict__ W2T,
                        const float* __restrict__ eb2,
                        float* agg)
{
    int e = blockIdx.x * 256 + threadIdx.x;
    if (e >= N_EDGES) return;
    int row = edge_index[e];
    int col = edge_index[N_EDGES + e];
    float h[H_NF];
    #pragma unroll
    for (int j = 0; j < H_NF; ++j) h[j] = eb1[j];
    const float* srcp = node_feats + (size_t)row * NODE_NF;
    #pragma unroll 1
    for (int k = 0; k < NODE_NF; ++k) {
        float x = srcp[k];
        const float* w = eW1 + k * H_NF;
        #pragma unroll
        for (int j = 0; j < H_NF; ++j) h[j] = fmaf(x, w[j], h[j]);
    }
    const float* dstp = node_feats + (size_t)col * NODE_NF;
    #pragma unroll 1
    for (int k = 0; k < NODE_NF; ++k) {
        float x = dstp[k];
        const float* w = eW1 + (NODE_NF + k) * H_NF;
        #pragma unroll
        for (int j = 0; j < H_NF; ++j) h[j] = fmaf(x, w[j], h[j]);
    }
    float4 at = ((const float4*)edge_attr)[e];
    float av[EDGE_NF] = {at.x, at.y, at.z, at.w};
    #pragma unroll
    for (int k = 0; k < EDGE_NF; ++k) {
        float x = av[k];
        const float* w = eW1 + (2 * NODE_NF + k) * H_NF;
        #pragma unroll
        for (int j = 0; j < H_NF; ++j) h[j] = fmaf(x, w[j], h[j]);
    }
    #pragma unroll
    for (int j = 0; j < H_NF; ++j) h[j] = fmaxf(h[j], 0.f);
    #pragma unroll 1
    for (int j0 = 0; j0 < H_NF; j0 += 8) {
        float acc[8];
        #pragma unroll
        for (int jj = 0; jj < 8; ++jj) acc[jj] = eb2[j0 + jj];
        #pragma unroll
        for (int k = 0; k < H_NF; ++k) {
            float x = h[k];
            #pragma unroll
            for (int jj = 0; jj < 8; ++jj)
                acc[jj] = fmaf(x, W2T[(j0 + jj) * H_NF + k], acc[jj]);
        }
        #pragma unroll
        for (int jj = 0; jj < 8; ++jj)
            unsafeAtomicAdd(&agg[(size_t)row * H_NF + j0 + jj], fmaxf(acc[jj], 0.f));
    }
}

__global__ __launch_bounds__(256)
void node_kernel1(const float* __restrict__ node_feats, float* agg_nh,
                  const float* __restrict__ nW1, const float* __restrict__ nb1)
{
    int n = blockIdx.x * 256 + threadIdx.x;
    if (n >= N_NODES) return;
    float acc[H_NF];
    #pragma unroll
    for (int j = 0; j < H_NF; ++j) acc[j] = nb1[j];
    const float* nfp = node_feats + (size_t)n * NODE_NF;
    #pragma unroll 1
    for (int k = 0; k < NODE_NF; ++k) {
        float x = nfp[k];
        const float* w = nW1 + k * H_NF;
        #pragma unroll
        for (int j = 0; j < H_NF; ++j) acc[j] = fmaf(x, w[j], acc[j]);
    }
    const float4* ap = (const float4*)(agg_nh + (size_t)n * H_NF);
    #pragma unroll 1
    for (int k4 = 0; k4 < H_NF / 4; ++k4) {
        float4 x = ap[k4];
        const float* w0 = nW1 + (NODE_NF + k4 * 4 + 0) * H_NF;
        const float* w1 = nW1 + (NODE_NF + k4 * 4 + 1) * H_NF;
        const float* w2 = nW1 + (NODE_NF + k4 * 4 + 2) * H_NF;
        const float* w3 = nW1 + (NODE_NF + k4 * 4 + 3) * H_NF;
        #pragma unroll
        for (int j = 0; j < H_NF; ++j) {
            acc[j] = fmaf(x.x, w0[j], acc[j]);
            acc[j] = fmaf(x.y, w1[j], acc[j]);
            acc[j] = fmaf(x.z, w2[j], acc[j]);
            acc[j] = fmaf(x.w, w3[j], acc[j]);
        }
    }
    float* op = agg_nh + (size_t)n * H_NF;
    #pragma unroll
    for (int j4 = 0; j4 < H_NF / 4; ++j4) {
        float4 o = make_float4(fmaxf(acc[j4*4+0], 0.f), fmaxf(acc[j4*4+1], 0.f),
                               fmaxf(acc[j4*4+2], 0.f), fmaxf(acc[j4*4+3], 0.f));
        ((float4*)op)[j4] = o;
    }
}

__global__ __launch_bounds__(256)
void node_kernel2(const float* __restrict__ nh, const float* __restrict__ nW2,
                  const float* __restrict__ nb2, const float* __restrict__ fW,
                  const float* __restrict__ fb, float* __restrict__ out)
{
    int n = blockIdx.x * 256 + threadIdx.x;
    if (n >= N_NODES) return;
    float acc[H_NF];
    #pragma unroll
    for (int j = 0; j < H_NF; ++j) acc[j] = nb2[j];
    const float4* hp = (const float4*)(nh + (size_t)n * H_NF);
    #pragma unroll 1
    for (int k4 = 0; k4 < H_NF / 4; ++k4) {
        float4 x = hp[k4];
        const float* w0 = nW2 + (k4 * 4 + 0) * H_NF;
        const float* w1 = nW2 + (k4 * 4 + 1) * H_NF;
        const float* w2 = nW2 + (k4 * 4 + 2) * H_NF;
        const float* w3 = nW2 + (k4 * 4 + 3) * H_NF;
        #pragma unroll
        for (int j = 0; j < H_NF; ++j) {
            acc[j] = fmaf(x.x, w0[j], acc[j]);
            acc[j] = fmaf(x.y, w1[j], acc[j]);
            acc[j] = fmaf(x.z, w2[j], acc[j]);
            acc[j] = fmaf(x.w, w3[j], acc[j]);
        }
    }
    float o0 = fb[0], o1 = fb[1], o2 = fb[2], o3 = fb[3];
    #pragma unroll
    for (int j = 0; j < H_NF; ++j) {
        o0 = fmaf(acc[j], fW[j * 4 + 0], o0);
        o1 = fmaf(acc[j], fW[j * 4 + 1], o1);
        o2 = fmaf(acc[j], fW[j * 4 + 2], o2);
        o3 = fmaf(acc[j], fW[j * 4 + 3], o3);
    }
    ((float4*)out)[n] = make_float4(o0, o1, o2, o3);
}

extern "C" void kernel_launch(void* const* d_in, const int* in_sizes, int n_in,
                              void* d_out, int out_size, void* d_ws, size_t ws_size,
                              hipStream_t stream)
{
    const float* node_feats = (const float*)d_in[0];
    const int*   edge_index = (const int*)d_in[1];
    const float* edge_attr  = (const float*)d_in[2];
    const float* eW1 = (const float*)d_in[3];
    const float* eb1 = (const float*)d_in[4];
    const float* eW2 = (const float*)d_in[5];
    const float* eb2 = (const float*)d_in[6];
    const float* nW1 = (const float*)d_in[7];
    const float* nb1 = (const float*)d_in[8];
    const float* nW2 = (const float*)d_in[9];
    const float* nb2 = (const float*)d_in[10];
    const float* fW  = (const float*)d_in[11];
    const float* fb  = (const float*)d_in[12];
    float* out = (float*)d_out;

    // ---- workspace carve-up (256B aligned). agg+hist adjacent -> ONE memset.
    size_t off = 0;
    auto carve = [&](size_t bytes) {
        void* p = (char*)d_ws + off;
        off = (off + bytes + 255) & ~(size_t)255;
        return p;
    };
    float*     agg    = (float*)carve((size_t)N_NODES * H_NF * sizeof(float)); // 51.2 MB
    int*       hist   = (int*)  carve((size_t)N_NODES * sizeof(int));
    size_t zero_bytes = off;   // agg + hist (contiguous from d_ws base)
    int*       starts = (int*)  carve((size_t)(N_NODES + 1) * sizeof(int));
    int*       cursor = (int*)  carve((size_t)N_NODES * sizeof(int));
    int*       bsum   = (int*)  carve((size_t)(NBLK + 1) * sizeof(int));
    _Float16*  nfh    = (_Float16*)carve((size_t)N_NODES * 12 * sizeof(_Float16)); // 2.4 MB
    _Float16*  w1h    = (_Float16*)carve((size_t)H_NF * K1P * sizeof(_Float16));
    _Float16*  w2h    = (_Float16*)carve((size_t)H_NF * K2P * sizeof(_Float16));
    _Float16*  w1nh   = (_Float16*)carve((size_t)H_NF * K1N * sizeof(_Float16));
    _Float16*  w23h   = (_Float16*)carve((size_t)16 * K2P * sizeof(_Float16));
    float*     b23    = (float*)carve(4 * sizeof(float));
    int*       perm   = (int*)  carve((size_t)N_EDGES * sizeof(int));          // tier-2 only
    size_t required_t2 = off;
    _Float16*  Asort  = (_Float16*)carve((size_t)N_EDGES * ASP * sizeof(_Float16)); // 102.4 MB
    int*       rowsS  = (int*)carve((size_t)N_EDGES * sizeof(int));                 // 6.4 MB
    size_t required_t1 = off;

    if (ws_size >= required_t2) {
        hipMemsetAsync(d_ws, 0, zero_bytes, stream);
        prep_hist_kernel<<<(SEG5 + 255) / 256, 256, 0, stream>>>(
            node_feats, eW1, eW2, nW1, nW2, fW, nb2, fb, edge_index,
            nfh, w1h, w2h, w1nh, w23h, b23, hist);
        scan1_kernel<<<NBLK, SCAN_B, 0, stream>>>(hist, starts, bsum);
        scan2_kernel<<<1, 64, 0, stream>>>(bsum);
        scan3_kernel<<<(N_NODES + 255) / 256, 256, 0, stream>>>(starts, cursor, bsum);

        if (ws_size >= required_t1) {
            permgather_kernel<<<(N_EDGES + 255) / 256, 256, 0, stream>>>(
                edge_index, nfh, edge_attr, cursor, Asort, rowsS);
            edge_mfma_kernel<<<512, 256, 0, stream>>>(
                Asort, rowsS, w1h, eb1, w2h, eb2, agg);
        } else {
            permute_kernel<<<(N_EDGES + 255) / 256, 256, 0, stream>>>(edge_index, cursor, perm);
            edge_mfma_gather_kernel<<<512, 256, 0, stream>>>(
                nfh, edge_index, edge_attr, w1h, eb1, w2h, eb2, perm, agg);
        }
        node_mfma_kernel<<<512, 256, 0, stream>>>(
            node_feats, agg, w1nh, nb1, w23h, b23, out);
    } else {
        // tier 3: fp32 atomic scatter path
        float* agg_fb = (float*)d_ws;
        float* W2T_fb = (float*)((char*)d_ws + (size_t)N_NODES * H_NF * sizeof(float));
        transpose_w2<<<(H_NF * H_NF + 255) / 256, 256, 0, stream>>>(eW2, W2T_fb);
        hipMemsetAsync(agg_fb, 0, (size_t)N_NODES * H_NF * sizeof(float), stream);
        edge_kernel_atomic<<<(N_EDGES + 255) / 256, 256, 0, stream>>>(
            node_feats, edge_index, edge_attr, eW1, eb1, W2T_fb, eb2, agg_fb);
        node_kernel1<<<(N_NODES + 255) / 256, 256, 0, stream>>>(node_feats, agg_fb, nW1, nb1);
        node_kernel2<<<(N_NODES + 255) / 256, 256, 0, stream>>>(agg_fb, nW2, nb2, fW, fb, out);
    }
}

// Round 10
// 424.197 us; speedup vs baseline: 1.4394x; 1.1181x over previous
//
#include <hip/hip_runtime.h>

#define N_NODES 100000
#define N_EDGES 1600000
#define NODE_NF 11
#define EDGE_NF 4
#define H_NF 128
#define SCAN_B 1024
#define NBLK ((N_NODES + SCAN_B - 1) / SCAN_B)   // 98

// Edge-MLP input layout (halves): src@0..10, 0@11, dst@12..22, 0@23,
// attr@24..27, 0@28..31. K=32 MFMA window covers 0..31.
#define K1P 40    // w1h row stride (halves)
#define K2P 136   // h / w2h row stride (halves)
#define EFP 131   // ef row stride (floats) — tier-2 kernel only
#define K1N 160   // node layer-1 padded K

typedef _Float16 half8 __attribute__((ext_vector_type(8)));
typedef float floatx4 __attribute__((ext_vector_type(4)));

__device__ inline half8 load8f(const float* p) {
    float4 x0 = *(const float4*)(p);
    float4 x1 = *(const float4*)(p + 4);
    half8 r;
    r[0]=(_Float16)x0.x; r[1]=(_Float16)x0.y; r[2]=(_Float16)x0.z; r[3]=(_Float16)x0.w;
    r[4]=(_Float16)x1.x; r[5]=(_Float16)x1.y; r[6]=(_Float16)x1.z; r[7]=(_Float16)x1.w;
    return r;
}
__device__ inline half8 zero8() {
    half8 z;
    #pragma unroll
    for (int j = 0; j < 8; ++j) z[j] = (_Float16)0.f;
    return z;
}

// ---------------------------------------------------------------------------
// Fused prep + hist (one launch, flat-index segments).
// ---------------------------------------------------------------------------
#define SEG0 (N_NODES * 12)            // nfh
#define SEG1 (SEG0 + H_NF * K1P)       // w1h
#define SEG2 (SEG1 + H_NF * K2P)       // w2h
#define SEG3 (SEG2 + H_NF * K1N)       // w1nh
#define SEG4 (SEG3 + 16 * K2P + 4)     // w23h + b23
#define SEG5 (SEG4 + N_EDGES)          // hist

__global__ __launch_bounds__(256)
void prep_hist_kernel(const float* __restrict__ nf,
                      const float* __restrict__ eW1,
                      const float* __restrict__ eW2,
                      const float* __restrict__ nW1,
                      const float* __restrict__ nW2,
                      const float* __restrict__ fW,
                      const float* __restrict__ nb2,
                      const float* __restrict__ fb,
                      const int*   __restrict__ edge_index,
                      _Float16* __restrict__ nfh,
                      _Float16* __restrict__ w1h,
                      _Float16* __restrict__ w2h,
                      _Float16* __restrict__ w1nh,
                      _Float16* __restrict__ w23h,
                      float* __restrict__ b23,
                      int* hist)
{
    int i = blockIdx.x * 256 + threadIdx.x;
    if (i < SEG0) {
        int n = i / 12, k = i - n * 12;
        nfh[i] = (k < NODE_NF) ? (_Float16)nf[(size_t)n * NODE_NF + k] : (_Float16)0.f;
    } else if (i < SEG1) {
        int j = i - SEG0;
        int n = j / K1P, k = j - n * K1P;
        float v = 0.f;
        if (k < 11)                 v = eW1[k * H_NF + n];
        else if (k >= 12 && k < 23) v = eW1[(k - 1) * H_NF + n];
        else if (k >= 24 && k < 28) v = eW1[(k - 2) * H_NF + n];
        w1h[j] = (_Float16)v;
    } else if (i < SEG2) {
        int j = i - SEG1;
        int n = j / K2P, k = j - n * K2P;
        w2h[j] = (k < H_NF) ? (_Float16)eW2[k * H_NF + n] : (_Float16)0.f;
    } else if (i < SEG3) {
        int j = i - SEG2;
        int n = j / K1N, k = j - n * K1N;
        float v = 0.f;
        if (k < 11)                  v = nW1[k * H_NF + n];
        else if (k >= 12 && k < 140) v = nW1[(k - 1) * H_NF + n];
        w1nh[j] = (_Float16)v;
    } else if (i < SEG4) {
        int j = i - SEG3;
        if (j < 16 * K2P) {
            int n = j / K2P, k = j - n * K2P;
            float v = 0.f;
            if (n < 4 && k < H_NF) {
                for (int q = 0; q < H_NF; ++q) v += nW2[k * H_NF + q] * fW[q * 4 + n];
            }
            w23h[j] = (_Float16)v;
        } else {
            int o = j - 16 * K2P;
            float v = fb[o];
            for (int q = 0; q < H_NF; ++q) v += nb2[q] * fW[q * 4 + o];
            b23[o] = v;
        }
    } else if (i < SEG5) {
        int e = i - SEG4;
        atomicAdd(&hist[edge_index[e]], 1);
    }
}

__global__ __launch_bounds__(256)
void transpose_w2(const float* __restrict__ W, float* __restrict__ WT) {
    int i = blockIdx.x * 256 + threadIdx.x;
    if (i < H_NF * H_NF) {
        int k = i >> 7, j = i & (H_NF - 1);
        WT[j * H_NF + k] = W[i];
    }
}

// ---------------------------------------------------------------------------
// Scan chain.
// ---------------------------------------------------------------------------
__global__ __launch_bounds__(SCAN_B)
void scan1_kernel(const int* __restrict__ hist, int* starts, int* bsum) {
    __shared__ int buf[SCAN_B];
    int i = blockIdx.x * SCAN_B + threadIdx.x;
    int v = (i < N_NODES) ? hist[i] : 0;
    buf[threadIdx.x] = v;
    __syncthreads();
    for (int off = 1; off < SCAN_B; off <<= 1) {
        int t = (threadIdx.x >= off) ? buf[threadIdx.x - off] : 0;
        __syncthreads();
        buf[threadIdx.x] += t;
        __syncthreads();
    }
    if (i < N_NODES) starts[i] = buf[threadIdx.x] - v;
    if (threadIdx.x == SCAN_B - 1) bsum[blockIdx.x] = buf[SCAN_B - 1];
}

__global__ void scan2_kernel(int* bsum) {
    if (threadIdx.x == 0 && blockIdx.x == 0) {
        int run = 0;
        for (int b = 0; b < NBLK; ++b) { int t = bsum[b]; bsum[b] = run; run += t; }
        bsum[NBLK] = run;
    }
}

__global__ __launch_bounds__(256)
void scan3_kernel(int* starts, int* cursor, const int* __restrict__ bsum) {
    int i = blockIdx.x * 256 + threadIdx.x;
    if (i < N_NODES) {
        int s = starts[i] + bsum[i / SCAN_B];
        starts[i] = s;
        cursor[i] = s;
    }
    if (i == 0) starts[N_NODES] = bsum[NBLK];
}

// ---------------------------------------------------------------------------
// Permute into 16B records: rec[pos] = {row, col, attr01, attr23}.
// 25.6 MB buffer = 3.2 MB/XCD L2 slice -> scattered 16B stores coalesce into
// full lines in L2 (vs R9's 102 MB Asort scatter that wrote back 2x).
// ---------------------------------------------------------------------------
__global__ __launch_bounds__(256)
void permrec_kernel(const int* __restrict__ edge_index,
                    const float* __restrict__ edge_attr,
                    int* cursor,
                    int4* __restrict__ rec)
{
    int e = blockIdx.x * 256 + threadIdx.x;
    if (e >= N_EDGES) return;
    int row = edge_index[e];
    int col = edge_index[N_EDGES + e];
    float4 a4 = ((const float4*)edge_attr)[e];
    union { _Float16 h[4]; int2 v; } u;
    u.h[0] = (_Float16)a4.x; u.h[1] = (_Float16)a4.y;
    u.h[2] = (_Float16)a4.z; u.h[3] = (_Float16)a4.w;
    int pos = atomicAdd(&cursor[row], 1);
    rec[pos] = make_int4(row, col, u.v.x, u.v.y);
}

// Tier-2: classic permute (perm only).
__global__ __launch_bounds__(256)
void permute_kernel(const int* __restrict__ edge_index, int* cursor, int* perm) {
    int e = blockIdx.x * 256 + threadIdx.x;
    if (e < N_EDGES) {
        int pos = atomicAdd(&cursor[edge_index[e]], 1);
        perm[pos] = e;
    }
}

// ---------------------------------------------------------------------------
// Edge MLP v5: persistent, barrier-free, weights in registers, rec-driven.
// Per window: rec (coalesced, prefetched 1 ahead) -> nfh gather (L2-resident
// 2.4 MB, pipelined 1 window ahead) -> Ain LDS (1 KB/wave) -> 8 MFMA (L1) ->
// Hs -> 32 MFMA (L2) -> C-layout shuffle segmented reduction -> atomics.
// Rows come from rc.x via shuffles — no rows_sorted buffer, no Asort.
// ---------------------------------------------------------------------------
#define E_ARENA_SZ 5504   // Ain@0 (1024B) + Hs@1024 (4352B) + pad

__global__ __launch_bounds__(256, 2)
void edge_mfma_kernel(const int4* __restrict__ recs,
                      const _Float16* __restrict__ nfh,
                      const _Float16* __restrict__ w1h,
                      const float* __restrict__ eb1,
                      const _Float16* __restrict__ w2h,
                      const float* __restrict__ eb2,
                      float* agg)   // [N_NODES][H_NF]
{
    __shared__ __align__(16) char smem[4 * E_ARENA_SZ];
    int t = threadIdx.x;
    int wv = t >> 6, lane = t & 63;
    char* arena = smem + wv * E_ARENA_SZ;
    _Float16* Ain = (_Float16*)arena;            // [16][32] halves
    _Float16* Hs  = (_Float16*)(arena + 1024);   // [16][K2P] halves
    int m = lane & 15, quad = lane >> 4;

    // loop-invariant weight fragments -> registers
    half8 w1f[8], w2f[8][4];
    #pragma unroll
    for (int tile = 0; tile < 8; ++tile)
        w1f[tile] = *(const half8*)(w1h + (tile * 16 + m) * K1P + quad * 8);
    #pragma unroll
    for (int tile = 0; tile < 8; ++tile)
        #pragma unroll
        for (int ks = 0; ks < 4; ++ks)
            w2f[tile][ks] = *(const half8*)(w2h + (tile * 16 + m) * K2P + ks * 32 + quad * 8);
    float b1v[8], b2v[8];
    #pragma unroll
    for (int tile = 0; tile < 8; ++tile) {
        b1v[tile] = eb1[tile * 16 + m];
        b2v[tile] = eb2[tile * 16 + m];
    }

    const int nwin = N_EDGES / 16;           // 100000
    const int STRIDE = gridDim.x * 4;
    int win = blockIdx.x * 4 + wv;
    if (win >= nwin) return;

    // preamble: rec + nfh gather for the first window
    int4 rc = recs[win * 16 + m];            // 16 unique 16B addrs, L1-broadcast
    int2 g0 = make_int2(0, 0), g1 = g0, g2 = g0;
    if (quad < 2) {
        int node = (quad == 0) ? rc.x : rc.y;
        const int2* p = (const int2*)(nfh + (size_t)node * 12);
        g0 = p[0]; g1 = p[1]; g2 = p[2];
    }

    while (true) {
        int next = win + STRIDE;
        bool hn = next < nwin;
        int4 rcn = make_int4(0, 0, 0, 0);
        if (hn) rcn = recs[next * 16 + m];   // prefetch rec for next window

        // ---- build Ain row for edge m from prefetched regs ----
        _Float16* arow = Ain + m * 32;
        if (quad == 0) {                     // src halves 0..11 (11 = 0)
            ((int2*)arow)[0] = g0; ((int2*)arow)[1] = g1; ((int2*)arow)[2] = g2;
        } else if (quad == 1) {              // dst halves 12..23 (23 = 0)
            int2* d = (int2*)(arow + 12);
            d[0] = g0; d[1] = g1; d[2] = g2;
        } else if (quad == 2) {              // attr 24..27, zeros 28..31
            int2* d = (int2*)(arow + 24);
            d[0] = make_int2(rc.z, rc.w);
            d[1] = make_int2(0, 0);
        }

        half8 a1 = *(const half8*)(Ain + m * 32 + quad * 8);   // lgkm-ordered

        // ---- layer 1: 26(pad32) -> 128 ----
        #pragma unroll
        for (int tile = 0; tile < 8; ++tile) {
            floatx4 c = {0.f, 0.f, 0.f, 0.f};
            c = __builtin_amdgcn_mfma_f32_16x16x32_f16(a1, w1f[tile], c, 0, 0, 0);
            int n = tile * 16 + m;
            #pragma unroll
            for (int r = 0; r < 4; ++r)
                Hs[(quad * 4 + r) * K2P + n] = (_Float16)fmaxf(c[r] + b1v[tile], 0.f);
        }

        // ---- layer 2 A-frags ----
        half8 a2[4];
        #pragma unroll
        for (int ks = 0; ks < 4; ++ks)
            a2[ks] = *(const half8*)(Hs + m * K2P + ks * 32 + quad * 8);

        // ---- layer 2: 128 -> 128, values in registers (C-layout) ----
        float vals[32];
        #pragma unroll
        for (int tile = 0; tile < 8; ++tile) {
            floatx4 c = {0.f, 0.f, 0.f, 0.f};
            #pragma unroll
            for (int ks = 0; ks < 4; ++ks)
                c = __builtin_amdgcn_mfma_f32_16x16x32_f16(a2[ks], w2f[tile][ks], c, 0, 0, 0);
            #pragma unroll
            for (int r = 0; r < 4; ++r)
                vals[tile * 4 + r] = fmaxf(c[r] + b2v[tile], 0.f);
        }

        // ---- pipelined nfh gather for next window (rcn has arrived) ----
        int2 n0 = make_int2(0, 0), n1 = n0, n2 = n0;
        if (hn && quad < 2) {
            int node = (quad == 0) ? rcn.x : rcn.y;
            const int2* p = (const int2*)(nfh + (size_t)node * 12);
            n0 = p[0]; n1 = p[1]; n2 = p[2];
        }

        // ---- segmented reduction, rows via shuffles from rc.x ----
        int row = rc.x;                           // row of edge m (all quads)
        int rprev = __shfl(row, lane - 1);
        bool bi = (lane < 16) && (m == 0 || rprev != row);
        unsigned long long bm = __ballot(bi);
        unsigned mk = (unsigned)(bm & 0xFFFFull); // wave-uniform segment starts
        int er0 = __shfl(row, quad * 4 + 0);
        int er1 = __shfl(row, quad * 4 + 1);
        int er2 = __shfl(row, quad * 4 + 2);
        int er3 = __shfl(row, quad * 4 + 3);
        while (mk) {
            int start = __builtin_ctz(mk);        // wave-uniform
            mk &= mk - 1;
            int srow = __shfl(row, start);
            float s[8];
            #pragma unroll
            for (int tile = 0; tile < 8; ++tile) {
                float v = 0.f;
                if (er0 == srow) v += vals[tile * 4 + 0];
                if (er1 == srow) v += vals[tile * 4 + 1];
                if (er2 == srow) v += vals[tile * 4 + 2];
                if (er3 == srow) v += vals[tile * 4 + 3];
                s[tile] = v;
            }
            #pragma unroll
            for (int tile = 0; tile < 8; ++tile) {
                s[tile] += __shfl_xor(s[tile], 16);
                s[tile] += __shfl_xor(s[tile], 32);
            }
            if (quad == 0) {
                #pragma unroll
                for (int tile = 0; tile < 8; ++tile)
                    unsafeAtomicAdd(&agg[(size_t)srow * H_NF + tile * 16 + m], s[tile]);
            }
        }

        if (!hn) break;
        win = next; rc = rcn; g0 = n0; g1 = n1; g2 = n2;
    }
}

// ---------------------------------------------------------------------------
// Tier-2 edge kernel: in-kernel gather via perm (no rec buffer). LDS reduction.
// ---------------------------------------------------------------------------
#define G_W1      0
#define G_W2      10240
#define G_ARENA   45056
#define G_ARENA_SZ 8448
#define G_TOTAL   (G_ARENA + 4 * G_ARENA_SZ)

__global__ __launch_bounds__(256, 2)
void edge_mfma_gather_kernel(const _Float16* __restrict__ nfh,
                             const int*   __restrict__ edge_index,
                             const float* __restrict__ edge_attr,
                             const _Float16* __restrict__ w1h,
                             const float* __restrict__ eb1,
                             const _Float16* __restrict__ w2h,
                             const float* __restrict__ eb2,
                             const int*   __restrict__ perm,
                             float* agg)
{
    __shared__ __align__(16) char smem[G_TOTAL];
    _Float16* W1s = (_Float16*)(smem + G_W1);
    _Float16* W2s = (_Float16*)(smem + G_W2);
    int t = threadIdx.x;
    {
        const float4* g1 = (const float4*)w1h;
        float4* s1 = (float4*)W1s;
        for (int i = t; i < 640; i += 256) s1[i] = g1[i];
        const float4* g2 = (const float4*)w2h;
        float4* s2 = (float4*)W2s;
        for (int i = t; i < 2176; i += 256) s2[i] = g2[i];
    }
    __syncthreads();

    int wv = t >> 6, lane = t & 63;
    char* arena = smem + G_ARENA + wv * G_ARENA_SZ;
    _Float16* Ain  = (_Float16*)arena;
    _Float16* Hs   = (_Float16*)(arena + 1280);
    float*    efS  = (float*)arena;
    int*      rowsS = (int*)(arena + 8384);

    int m = lane & 15, quad = lane >> 4;
    int el = lane & 15, grp = lane >> 4;
    _Float16* arow = Ain + el * K1P;

    float b1v[8], b2v[8];
    #pragma unroll
    for (int tile = 0; tile < 8; ++tile) {
        b1v[tile] = eb1[tile * 16 + m];
        b2v[tile] = eb2[tile * 16 + m];
    }

    const int nwin = N_EDGES / 16;
    for (int win = blockIdx.x * 4 + wv; win < nwin; win += gridDim.x * 4) {
        int e = perm[win * 16 + el];
        if (grp < 2) {
            int node = edge_index[grp * N_EDGES + e];
            const int2* p = (const int2*)(nfh + (size_t)node * 12);
            int2 x0 = p[0], x1 = p[1], x2 = p[2];
            char* dst = (char*)(arow + grp * 12);
            *(int2*)(dst) = x0; *(int2*)(dst + 8) = x1; *(int2*)(dst + 16) = x2;
        } else if (grp == 2) {
            float4 a4 = ((const float4*)edge_attr)[e];
            arow[24] = (_Float16)a4.x; arow[25] = (_Float16)a4.y;
            arow[26] = (_Float16)a4.z; arow[27] = (_Float16)a4.w;
        } else {
            rowsS[el] = edge_index[e];
            *(int2*)((char*)arow + 56) = make_int2(0, 0);
        }

        half8 a1 = *(const half8*)(Ain + m * K1P + quad * 8);
        #pragma unroll
        for (int tile = 0; tile < 8; ++tile) {
            half8 b = *(const half8*)(W1s + (tile * 16 + m) * K1P + quad * 8);
            floatx4 c = {0.f, 0.f, 0.f, 0.f};
            c = __builtin_amdgcn_mfma_f32_16x16x32_f16(a1, b, c, 0, 0, 0);
            int n = tile * 16 + m;
            #pragma unroll
            for (int r = 0; r < 4; ++r)
                Hs[(quad * 4 + r) * K2P + n] = (_Float16)fmaxf(c[r] + b1v[tile], 0.f);
        }
        half8 a2[4];
        #pragma unroll
        for (int ks = 0; ks < 4; ++ks)
            a2[ks] = *(const half8*)(Hs + m * K2P + ks * 32 + quad * 8);
        #pragma unroll
        for (int tile = 0; tile < 8; ++tile) {
            floatx4 c = {0.f, 0.f, 0.f, 0.f};
            #pragma unroll
            for (int ks = 0; ks < 4; ++ks) {
                half8 b = *(const half8*)(W2s + (tile * 16 + m) * K2P + ks * 32 + quad * 8);
                c = __builtin_amdgcn_mfma_f32_16x16x32_f16(a2[ks], b, c, 0, 0, 0);
            }
            #pragma unroll
            for (int r = 0; r < 4; ++r)
                efS[(quad * 4 + r) * EFP + tile * 16 + m] = fmaxf(c[r] + b2v[tile], 0.f);
        }

        int f = lane;
        int cur = rowsS[0];
        float acc0 = efS[f], acc1 = efS[64 + f];
        #pragma unroll 1
        for (int i = 1; i < 16; ++i) {
            int r = rowsS[i];
            float v0 = efS[i * EFP + f];
            float v1 = efS[i * EFP + 64 + f];
            if (r != cur) {
                unsafeAtomicAdd(&agg[(size_t)cur * H_NF + f], acc0);
                unsafeAtomicAdd(&agg[(size_t)cur * H_NF + 64 + f], acc1);
                acc0 = v0; acc1 = v1; cur = r;
            } else { acc0 += v0; acc1 += v1; }
        }
        unsafeAtomicAdd(&agg[(size_t)cur * H_NF + f], acc0);
        unsafeAtomicAdd(&agg[(size_t)cur * H_NF + 64 + f], acc1);
    }
}

// ---------------------------------------------------------------------------
// Fused node pipeline, persistent, epilogue bias.
// ---------------------------------------------------------------------------
#define N_W1    0                         // 128*160*2 = 40960
#define N_W23   40960                     // 16*136*2  = 4352 -> 45312
#define N_HS    45312                     // + 4*4352 -> 62720

__global__ __launch_bounds__(256, 2)
void node_mfma_kernel(const float* __restrict__ node_feats,
                      const float* __restrict__ agg,
                      const _Float16* __restrict__ w1nh,
                      const float* __restrict__ nb1,
                      const _Float16* __restrict__ w23h,
                      const float* __restrict__ b23,
                      float* __restrict__ out)
{
    __shared__ __align__(16) char smem[N_HS + 4 * 4352];
    _Float16* W1N  = (_Float16*)(smem + N_W1);
    _Float16* W23s = (_Float16*)(smem + N_W23);
    int t = threadIdx.x;
    {
        const float4* g1 = (const float4*)w1nh;
        float4* s1 = (float4*)W1N;
        for (int i = t; i < 2560; i += 256) s1[i] = g1[i];
        const float4* g2 = (const float4*)w23h;
        float4* s2 = (float4*)W23s;
        for (int i = t; i < 272; i += 256) s2[i] = g2[i];
    }
    __syncthreads();

    int wv = t >> 6, lane = t & 63;
    int m = lane & 15, quad = lane >> 4;
    _Float16* HsW = (_Float16*)(smem + N_HS + wv * 4352);
    const int ntile = (N_NODES + 63) / 64;   // 1563

    float nb1v[8];
    #pragma unroll
    for (int tile = 0; tile < 8; ++tile) nb1v[tile] = nb1[tile * 16 + m];
    float b23v = (m < 4) ? b23[m] : 0.f;

    for (int ti = blockIdx.x; ti < ntile; ti += gridDim.x) {
        int nb = (ti * 4 + wv) * 16;
        if (nb >= N_NODES) continue;
        int nodeA = nb + m;
        if (nodeA >= N_NODES) nodeA = N_NODES - 1;
        const float* ag  = agg + (size_t)nodeA * H_NF;
        const float* nfp = node_feats + (size_t)nodeA * NODE_NF;

        half8 afr[5];
        if (quad == 0) {
            half8 r;
            #pragma unroll
            for (int j = 0; j < 8; ++j) r[j] = (_Float16)nfp[j];
            afr[0] = r;
            afr[4] = load8f(ag + 116);
        } else if (quad == 1) {
            half8 r;
            r[0] = (_Float16)nfp[8]; r[1] = (_Float16)nfp[9];
            r[2] = (_Float16)nfp[10]; r[3] = (_Float16)0.f;
            float4 x = *(const float4*)(ag);
            r[4] = (_Float16)x.x; r[5] = (_Float16)x.y;
            r[6] = (_Float16)x.z; r[7] = (_Float16)x.w;
            afr[0] = r;
            float4 y = *(const float4*)(ag + 124);
            half8 s = zero8();
            s[0] = (_Float16)y.x; s[1] = (_Float16)y.y;
            s[2] = (_Float16)y.z; s[3] = (_Float16)y.w;
            afr[4] = s;
        } else if (quad == 2) {
            afr[0] = load8f(ag + 4);
            afr[4] = zero8();
        } else {
            afr[0] = load8f(ag + 12);
            afr[4] = zero8();
        }
        afr[1] = load8f(ag + 20 + 8 * quad);
        afr[2] = load8f(ag + 52 + 8 * quad);
        afr[3] = load8f(ag + 84 + 8 * quad);

        #pragma unroll
        for (int tile = 0; tile < 8; ++tile) {
            floatx4 c = {0.f, 0.f, 0.f, 0.f};
            #pragma unroll
            for (int ks = 0; ks < 5; ++ks) {
                half8 b = *(const half8*)(W1N + (tile * 16 + m) * K1N + ks * 32 + quad * 8);
                c = __builtin_amdgcn_mfma_f32_16x16x32_f16(afr[ks], b, c, 0, 0, 0);
            }
            #pragma unroll
            for (int r = 0; r < 4; ++r)
                HsW[(quad * 4 + r) * K2P + tile * 16 + m] = (_Float16)fmaxf(c[r] + nb1v[tile], 0.f);
        }

        half8 a2[4];
        #pragma unroll
        for (int ks = 0; ks < 4; ++ks)
            a2[ks] = *(const half8*)(HsW + m * K2P + ks * 32 + quad * 8);
        floatx4 c23 = {0.f, 0.f, 0.f, 0.f};
        #pragma unroll
        for (int ks = 0; ks < 4; ++ks) {
            half8 b = *(const half8*)(W23s + m * K2P + ks * 32 + quad * 8);
            c23 = __builtin_amdgcn_mfma_f32_16x16x32_f16(a2[ks], b, c23, 0, 0, 0);
        }
        if (m < 4) {
            #pragma unroll
            for (int r = 0; r < 4; ++r) {
                int node = nb + quad * 4 + r;
                if (node < N_NODES) out[node * 4 + m] = c23[r] + b23v;
            }
        }
    }
}

// ---------------------------------------------------------------------------
// Tier-3 fp32 fallback.
// ---------------------------------------------------------------------------
__global__ __launch_bounds__(256)
void edge_kernel_atomic(const float* __restrict__ node_feats,
                        const int*   __restrict__ edge_index,
                        const float* __restrict__ edge_attr,
                        const float* __restrict__ eW1,
                        const float* __restrict__ eb1,
                        const float* __restrict__ W2T,
                        const float* __restrict__ eb2,
                        float* agg)
{
    int e = blockIdx.x * 256 + threadIdx.x;
    if (e >= N_EDGES) return;
    int row = edge_index[e];
    int col = edge_index[N_EDGES + e];
    float h[H_NF];
    #pragma unroll
    for (int j = 0; j < H_NF; ++j) h[j] = eb1[j];
    const float* srcp = node_feats + (size_t)row * NODE_NF;
    #pragma unroll 1
    for (int k = 0; k < NODE_NF; ++k) {
        float x = srcp[k];
        const float* w = eW1 + k * H_NF;
        #pragma unroll
        for (int j = 0; j < H_NF; ++j) h[j] = fmaf(x, w[j], h[j]);
    }
    const float* dstp = node_feats + (size_t)col * NODE_NF;
    #pragma unroll 1
    for (int k = 0; k < NODE_NF; ++k) {
        float x = dstp[k];
        const float* w = eW1 + (NODE_NF + k) * H_NF;
        #pragma unroll
        for (int j = 0; j < H_NF; ++j) h[j] = fmaf(x, w[j], h[j]);
    }
    float4 at = ((const float4*)edge_attr)[e];
    float av[EDGE_NF] = {at.x, at.y, at.z, at.w};
    #pragma unroll
    for (int k = 0; k < EDGE_NF; ++k) {
        float x = av[k];
        const float* w = eW1 + (2 * NODE_NF + k) * H_NF;
        #pragma unroll
        for (int j = 0; j < H_NF; ++j) h[j] = fmaf(x, w[j], h[j]);
    }
    #pragma unroll
    for (int j = 0; j < H_NF; ++j) h[j] = fmaxf(h[j], 0.f);
    #pragma unroll 1
    for (int j0 = 0; j0 < H_NF; j0 += 8) {
        float acc[8];
        #pragma unroll
        for (int jj = 0; jj < 8; ++jj) acc[jj] = eb2[j0 + jj];
        #pragma unroll
        for (int k = 0; k < H_NF; ++k) {
            float x = h[k];
            #pragma unroll
            for (int jj = 0; jj < 8; ++jj)
                acc[jj] = fmaf(x, W2T[(j0 + jj) * H_NF + k], acc[jj]);
        }
        #pragma unroll
        for (int jj = 0; jj < 8; ++jj)
            unsafeAtomicAdd(&agg[(size_t)row * H_NF + j0 + jj], fmaxf(acc[jj], 0.f));
    }
}

__global__ __launch_bounds__(256)
void node_kernel1(const float* __restrict__ node_feats, float* agg_nh,
                  const float* __restrict__ nW1, const float* __restrict__ nb1)
{
    int n = blockIdx.x * 256 + threadIdx.x;
    if (n >= N_NODES) return;
    float acc[H_NF];
    #pragma unroll
    for (int j = 0; j < H_NF; ++j) acc[j] = nb1[j];
    const float* nfp = node_feats + (size_t)n * NODE_NF;
    #pragma unroll 1
    for (int k = 0; k < NODE_NF; ++k) {
        float x = nfp[k];
        const float* w = nW1 + k * H_NF;
        #pragma unroll
        for (int j = 0; j < H_NF; ++j) acc[j] = fmaf(x, w[j], acc[j]);
    }
    const float4* ap = (const float4*)(agg_nh + (size_t)n * H_NF);
    #pragma unroll 1
    for (int k4 = 0; k4 < H_NF / 4; ++k4) {
        float4 x = ap[k4];
        const float* w0 = nW1 + (NODE_NF + k4 * 4 + 0) * H_NF;
        const float* w1 = nW1 + (NODE_NF + k4 * 4 + 1) * H_NF;
        const float* w2 = nW1 + (NODE_NF + k4 * 4 + 2) * H_NF;
        const float* w3 = nW1 + (NODE_NF + k4 * 4 + 3) * H_NF;
        #pragma unroll
        for (int j = 0; j < H_NF; ++j) {
            acc[j] = fmaf(x.x, w0[j], acc[j]);
            acc[j] = fmaf(x.y, w1[j], acc[j]);
            acc[j] = fmaf(x.z, w2[j], acc[j]);
            acc[j] = fmaf(x.w, w3[j], acc[j]);
        }
    }
    float* op = agg_nh + (size_t)n * H_NF;
    #pragma unroll
    for (int j4 = 0; j4 < H_NF / 4; ++j4) {
        float4 o = make_float4(fmaxf(acc[j4*4+0], 0.f), fmaxf(acc[j4*4+1], 0.f),
                               fmaxf(acc[j4*4+2], 0.f), fmaxf(acc[j4*4+3], 0.f));
        ((float4*)op)[j4] = o;
    }
}

__global__ __launch_bounds__(256)
void node_kernel2(const float* __restrict__ nh, const float* __restrict__ nW2,
                  const float* __restrict__ nb2, const float* __restrict__ fW,
                  const float* __restrict__ fb, float* __restrict__ out)
{
    int n = blockIdx.x * 256 + threadIdx.x;
    if (n >= N_NODES) return;
    float acc[H_NF];
    #pragma unroll
    for (int j = 0; j < H_NF; ++j) acc[j] = nb2[j];
    const float4* hp = (const float4*)(nh + (size_t)n * H_NF);
    #pragma unroll 1
    for (int k4 = 0; k4 < H_NF / 4; ++k4) {
        float4 x = hp[k4];
        const float* w0 = nW2 + (k4 * 4 + 0) * H_NF;
        const float* w1 = nW2 + (k4 * 4 + 1) * H_NF;
        const float* w2 = nW2 + (k4 * 4 + 2) * H_NF;
        const float* w3 = nW2 + (k4 * 4 + 3) * H_NF;
        #pragma unroll
        for (int j = 0; j < H_NF; ++j) {
            acc[j] = fmaf(x.x, w0[j], acc[j]);
            acc[j] = fmaf(x.y, w1[j], acc[j]);
            acc[j] = fmaf(x.z, w2[j], acc[j]);
            acc[j] = fmaf(x.w, w3[j], acc[j]);
        }
    }
    float o0 = fb[0], o1 = fb[1], o2 = fb[2], o3 = fb[3];
    #pragma unroll
    for (int j = 0; j < H_NF; ++j) {
        o0 = fmaf(acc[j], fW[j * 4 + 0], o0);
        o1 = fmaf(acc[j], fW[j * 4 + 1], o1);
        o2 = fmaf(acc[j], fW[j * 4 + 2], o2);
        o3 = fmaf(acc[j], fW[j * 4 + 3], o3);
    }
    ((float4*)out)[n] = make_float4(o0, o1, o2, o3);
}

extern "C" void kernel_launch(void* const* d_in, const int* in_sizes, int n_in,
                              void* d_out, int out_size, void* d_ws, size_t ws_size,
                              hipStream_t stream)
{
    const float* node_feats = (const float*)d_in[0];
    const int*   edge_index = (const int*)d_in[1];
    const float* edge_attr  = (const float*)d_in[2];
    const float* eW1 = (const float*)d_in[3];
    const float* eb1 = (const float*)d_in[4];
    const float* eW2 = (const float*)d_in[5];
    const float* eb2 = (const float*)d_in[6];
    const float* nW1 = (const float*)d_in[7];
    const float* nb1 = (const float*)d_in[8];
    const float* nW2 = (const float*)d_in[9];
    const float* nb2 = (const float*)d_in[10];
    const float* fW  = (const float*)d_in[11];
    const float* fb  = (const float*)d_in[12];
    float* out = (float*)d_out;

    // ---- workspace carve-up (256B aligned). agg+hist adjacent -> ONE memset.
    size_t off = 0;
    auto carve = [&](size_t bytes) {
        void* p = (char*)d_ws + off;
        off = (off + bytes + 255) & ~(size_t)255;
        return p;
    };
    float*     agg    = (float*)carve((size_t)N_NODES * H_NF * sizeof(float)); // 51.2 MB
    int*       hist   = (int*)  carve((size_t)N_NODES * sizeof(int));
    size_t zero_bytes = off;   // agg + hist (contiguous from d_ws base)
    int*       starts = (int*)  carve((size_t)(N_NODES + 1) * sizeof(int));
    int*       cursor = (int*)  carve((size_t)N_NODES * sizeof(int));
    int*       bsum   = (int*)  carve((size_t)(NBLK + 1) * sizeof(int));
    _Float16*  nfh    = (_Float16*)carve((size_t)N_NODES * 12 * sizeof(_Float16)); // 2.4 MB
    _Float16*  w1h    = (_Float16*)carve((size_t)H_NF * K1P * sizeof(_Float16));
    _Float16*  w2h    = (_Float16*)carve((size_t)H_NF * K2P * sizeof(_Float16));
    _Float16*  w1nh   = (_Float16*)carve((size_t)H_NF * K1N * sizeof(_Float16));
    _Float16*  w23h   = (_Float16*)carve((size_t)16 * K2P * sizeof(_Float16));
    float*     b23    = (float*)carve(4 * sizeof(float));
    int*       perm   = (int*)  carve((size_t)N_EDGES * sizeof(int));          // tier-2 only
    size_t required_t2 = off;
    int4*      rec    = (int4*) carve((size_t)N_EDGES * sizeof(int4));         // 25.6 MB
    size_t required_t1 = off;

    if (ws_size >= required_t2) {
        hipMemsetAsync(d_ws, 0, zero_bytes, stream);
        prep_hist_kernel<<<(SEG5 + 255) / 256, 256, 0, stream>>>(
            node_feats, eW1, eW2, nW1, nW2, fW, nb2, fb, edge_index,
            nfh, w1h, w2h, w1nh, w23h, b23, hist);
        scan1_kernel<<<NBLK, SCAN_B, 0, stream>>>(hist, starts, bsum);
        scan2_kernel<<<1, 64, 0, stream>>>(bsum);
        scan3_kernel<<<(N_NODES + 255) / 256, 256, 0, stream>>>(starts, cursor, bsum);

        if (ws_size >= required_t1) {
            permrec_kernel<<<(N_EDGES + 255) / 256, 256, 0, stream>>>(
                edge_index, edge_attr, cursor, rec);
            edge_mfma_kernel<<<512, 256, 0, stream>>>(
                rec, nfh, w1h, eb1, w2h, eb2, agg);
        } else {
            permute_kernel<<<(N_EDGES + 255) / 256, 256, 0, stream>>>(edge_index, cursor, perm);
            edge_mfma_gather_kernel<<<512, 256, 0, stream>>>(
                nfh, edge_index, edge_attr, w1h, eb1, w2h, eb2, perm, agg);
        }
        node_mfma_kernel<<<512, 256, 0, stream>>>(
            node_feats, agg, w1nh, nb1, w23h, b23, out);
    } else {
        // tier 3: fp32 atomic scatter path
        float* agg_fb = (float*)d_ws;
        float* W2T_fb = (float*)((char*)d_ws + (size_t)N_NODES * H_NF * sizeof(float));
        transpose_w2<<<(H_NF * H_NF + 255) / 256, 256, 0, stream>>>(eW2, W2T_fb);
        hipMemsetAsync(agg_fb, 0, (size_t)N_NODES * H_NF * sizeof(float), stream);
        edge_kernel_atomic<<<(N_EDGES + 255) / 256, 256, 0, stream>>>(
            node_feats, edge_index, edge_attr, eW1, eb1, W2T_fb, eb2, agg_fb);
        node_kernel1<<<(N_NODES + 255) / 256, 256, 0, stream>>>(node_feats, agg_fb, nW1, nb1);
        node_kernel2<<<(N_NODES + 255) / 256, 256, 0, stream>>>(agg_fb, nW2, nb2, fW, fb, out);
    }
}